// Round 5
// baseline (343.110 us; speedup 1.0000x reference)
//
#include <hip/hip_runtime.h>
#include <math.h>

#define IN_DIM 128
#define HID 64
#define NEG_SLOPE 0.2f
#define CHUNK 4096
#define SMEM_UNION 53248
#define NBIGBLK 40

typedef __attribute__((ext_vector_type(8))) short bf16x8;
typedef __attribute__((ext_vector_type(4))) float f32x4;
typedef __attribute__((ext_vector_type(2))) float v2f;

__device__ __forceinline__ float wmax(float v){
  #pragma unroll
  for (int o = 32; o > 0; o >>= 1) v = fmaxf(v, __shfl_xor(v, o));
  return v;
}
__device__ __forceinline__ float wsum(float v){
  #pragma unroll
  for (int o = 32; o > 0; o >>= 1) v += __shfl_xor(v, o);
  return v;
}
__device__ __forceinline__ float wmax32(float v){
  #pragma unroll
  for (int o = 16; o > 0; o >>= 1) v = fmaxf(v, __shfl_xor(v, o, 32));
  return v;
}
__device__ __forceinline__ unsigned short f2bf(float f){
  union { float f; unsigned u; } v; v.f = f;
  unsigned r = v.u + 0x7fffu + ((v.u >> 16) & 1u);
  return (unsigned short)(r >> 16);
}
__device__ __forceinline__ float bl(unsigned u){
  union { unsigned u; float f; } v; v.u = u << 16; return v.f;
}
__device__ __forceinline__ float bh(unsigned u){
  union { unsigned u; float f; } v; v.u = u & 0xffff0000u; return v.f;
}
__device__ __forceinline__ v2f up2(unsigned u){
  v2f r; r[0] = bl(u); r[1] = bh(u); return r;
}

// ---------- CSR build: direct counting sort ----------
// Old 3-phase radix (pack+hist -> scatter-by-hi8 -> group-by-lo8) had ~48
// barriers/block, two LDS-atomic passes, and 2x 3.4MB round-trips. Consumers
// only need edges grouped by dst (any order within a node -- order was already
// nondeterministic). Direct: global deg histogram -> single-block scan ->
// atomic scatter. 850k L2-resident atomics are cheap (G12/m20).

__global__ __launch_bounds__(256) void prep(const int* __restrict__ ei, int E, int NBLK,
                                            int* __restrict__ deg,
                                            const float* __restrict__ W1,
                                            const float* __restrict__ W2,
                                            unsigned short* __restrict__ W1t,
                                            unsigned short* __restrict__ W2t){
  int tid = threadIdx.x;
  if ((int)blockIdx.x < NBLK){
    int base = blockIdx.x * CHUNK;
    #pragma unroll
    for (int j = 0; j < CHUNK / 256; j++){
      int e = base + j * 256 + tid;
      if (e < E) atomicAdd(&deg[ei[E + e]], 1);
    }
  } else {
    int t = (blockIdx.x - NBLK) * 256 + tid;
    if (t < 128 * 128){
      int n = t >> 7, k = t & 127;
      W1t[n * 128 + k] = f2bf(W1[k * 128 + n]);
    }
    int t2 = t - 128 * 128;
    if (t2 >= 0 && t2 < 64 * 64){
      int n = t2 >> 6, k = t2 & 63;
      W2t[n * 64 + k] = f2bf(W2[k * 64 + n]);
    }
  }
}

// single block, 1024 threads: exclusive scan of deg[0..N) -> row_ptr, cur
__global__ __launch_bounds__(1024) void scan_seed(const int* __restrict__ deg,
                                                  int* __restrict__ row_ptr,
                                                  int* __restrict__ cur, int N, int E){
  __shared__ int part[1024];
  int tid = threadIdx.x;
  int per = (N + 1023) >> 10;
  int a = tid * per; if (a > N) a = N;
  int b = a + per;   if (b > N) b = N;
  int lsum = 0;
  for (int i = a; i < b; i++) lsum += deg[i];
  part[tid] = lsum;
  __syncthreads();
  #pragma unroll
  for (int off = 1; off < 1024; off <<= 1){
    int v = part[tid];
    if (tid >= off) v += part[tid - off];
    __syncthreads();
    part[tid] = v;
    __syncthreads();
  }
  int run = tid ? part[tid - 1] : 0;
  for (int i = a; i < b; i++){
    row_ptr[i] = run; cur[i] = run; run += deg[i];
  }
  if (tid == 0) row_ptr[N] = E;
}

__device__ void scatter_direct(const int* __restrict__ ei, int E, int* __restrict__ cur,
                               unsigned* __restrict__ sorted, int bx){
  int base = bx * CHUNK;
  int tid = threadIdx.x;
  #pragma unroll
  for (int j = 0; j < CHUNK / 256; j++){
    int e = base + j * 256 + tid;
    if (e < E){
      int s_ = ei[e];
      int d_ = ei[E + e];
      int pos = atomicAdd(&cur[d_], 1);
      sorted[pos] = (unsigned)s_;
    }
  }
}

// ---------- layer-1 GEMM body (MT=64, K=128, NC=128, 2 heads, 256 threads) ----------

__device__ void gemm1_body(char* smem, const float* __restrict__ X,
                           const unsigned short* __restrict__ Wt,
                           const float* __restrict__ asrc, const float* __restrict__ adst,
                           unsigned short* __restrict__ Hb, float* __restrict__ aa,
                           int n_rows, int n0){
  const int KP = 136, CP = 132;
  unsigned short* xa = (unsigned short*)smem;   // [64][136]
  unsigned short* wl = xa + 64 * KP;            // [128][136]
  int tid = threadIdx.x;
  for (int idx = tid; idx < 64 * 32; idx += 256){
    int n = idx >> 5, k4 = idx & 31;
    float4 v = make_float4(0.f, 0.f, 0.f, 0.f);
    if (n0 + n < n_rows) v = *(const float4*)&X[(size_t)(n0 + n) * 128 + k4 * 4];
    ushort4 pk; pk.x = f2bf(v.x); pk.y = f2bf(v.y); pk.z = f2bf(v.z); pk.w = f2bf(v.w);
    *(ushort4*)&xa[n * KP + k4 * 4] = pk;
  }
  for (int idx = tid; idx < 128 * 16; idx += 256){
    int n = idx >> 4, k8 = idx & 15;
    uint4 v = *(const uint4*)&Wt[(size_t)n * 128 + k8 * 8];
    *(uint4*)&wl[n * KP + k8 * 8] = v;
  }
  __syncthreads();

  int lane = tid & 63, w = tid >> 6;
  int m = lane & 15, q = lane >> 4;
  f32x4 acc[4][2];
  #pragma unroll
  for (int i = 0; i < 4; i++)
    #pragma unroll
    for (int j = 0; j < 2; j++)
      #pragma unroll
      for (int r = 0; r < 4; r++) acc[i][j][r] = 0.f;
  #pragma unroll
  for (int ks = 0; ks < 4; ks++){
    bf16x8 bg[2];
    #pragma unroll
    for (int j = 0; j < 2; j++)
      bg[j] = *(const bf16x8*)&wl[((2 * w + j) * 16 + m) * KP + ks * 32 + q * 8];
    #pragma unroll
    for (int i = 0; i < 4; i++){
      bf16x8 af = *(const bf16x8*)&xa[(i * 16 + m) * KP + ks * 32 + q * 8];
      #pragma unroll
      for (int j = 0; j < 2; j++)
        acc[i][j] = __builtin_amdgcn_mfma_f32_16x16x32_bf16(af, bg[j], acc[i][j], 0, 0, 0);
    }
  }
  __syncthreads();
  float* C = (float*)smem;   // [64][132]
  #pragma unroll
  for (int i = 0; i < 4; i++)
    #pragma unroll
    for (int j = 0; j < 2; j++)
      #pragma unroll
      for (int r = 0; r < 4; r++)
        C[(i * 16 + q * 4 + r) * CP + (2 * w + j) * 16 + m] = acc[i][j][r];
  __syncthreads();

  int row = tid >> 2;
  int c0 = (tid & 3) * 32;
  int n = n0 + row;
  int head = (tid & 3) >> 1;
  float s_p = 0.f, d_p = 0.f;
  unsigned short hb[32];
  #pragma unroll
  for (int c = 0; c < 32; c += 4){
    f32x4 v = *(const f32x4*)&C[row * CP + c0 + c];
    #pragma unroll
    for (int u = 0; u < 4; u++){
      int ch = (c0 + c + u) & 63;
      s_p += v[u] * asrc[head * 64 + ch];
      d_p += v[u] * adst[head * 64 + ch];
      hb[c + u] = f2bf(v[u]);
    }
  }
  if (n < n_rows){
    #pragma unroll
    for (int c = 0; c < 32; c += 8){
      uint4 pk;
      pk.x = (unsigned)hb[c]     | ((unsigned)hb[c + 1] << 16);
      pk.y = (unsigned)hb[c + 2] | ((unsigned)hb[c + 3] << 16);
      pk.z = (unsigned)hb[c + 4] | ((unsigned)hb[c + 5] << 16);
      pk.w = (unsigned)hb[c + 6] | ((unsigned)hb[c + 7] << 16);
      *(uint4*)&Hb[(size_t)n * 128 + c0 + c] = pk;
    }
  }
  s_p += __shfl_xor(s_p, 1);
  d_p += __shfl_xor(d_p, 1);
  if ((tid & 1) == 0 && n < n_rows){
    aa[(size_t)n * 4 + head]     = s_p;
    aa[(size_t)n * 4 + 2 + head] = d_p;
  }
}

// combined: scatter blocks + gemm1 blocks in one launch
__global__ __launch_bounds__(256) void scatter_gemm(const int* __restrict__ ei, int E,
    int* __restrict__ cur, unsigned* __restrict__ sorted, int NS,
    const float* __restrict__ X, const unsigned short* __restrict__ W1t,
    const float* __restrict__ asrc1, const float* __restrict__ adst1,
    unsigned short* __restrict__ h1b, float* __restrict__ aa1, int n_rows){
  __shared__ char smem[SMEM_UNION];
  int bx = blockIdx.x;
  if (bx < NS){
    scatter_direct(ei, E, cur, sorted, bx);
  } else {
    gemm1_body(smem, X, W1t, asrc1, adst1, h1b, aa1, n_rows, (bx - NS) * 64);
  }
}

// ---------- layer-2 GEMM (bf16 input x1b, M-tile 128, 512 threads) ----------

__global__ __launch_bounds__(512) void gemm2_mfma(const unsigned short* __restrict__ Xb,
    const unsigned short* __restrict__ Wt, const float* __restrict__ asrc,
    const float* __restrict__ adst, unsigned short* __restrict__ Hb,
    float* __restrict__ aa, int n_rows)
{
  constexpr int K = 64, NC = 64;
  constexpr int MT = 128;
  constexpr int KP = K + 8;
  constexpr int CP = NC + 4;
  constexpr int MFW = 4;
  constexpr unsigned SM1 = (unsigned)(MT + NC) * KP * 2;
  constexpr unsigned SM2 = (unsigned)MT * CP * 4;
  __shared__ char smem[SM1 > SM2 ? SM1 : SM2];
  unsigned short* xa = (unsigned short*)smem;
  unsigned short* wl = xa + MT * KP;
  int tid = threadIdx.x;
  int n0 = blockIdx.x * MT;

  for (int idx = tid; idx < MT * (K / 8); idx += 512){
    int n = idx >> 3, k8 = idx & 7;
    uint4 v = make_uint4(0u, 0u, 0u, 0u);
    if (n0 + n < n_rows) v = *(const uint4*)&Xb[(size_t)(n0 + n) * K + k8 * 8];
    *(uint4*)&xa[n * KP + k8 * 8] = v;
  }
  for (int idx = tid; idx < NC * (K / 8); idx += 512){
    int n = idx >> 3, k8 = idx & 7;
    uint4 v = *(const uint4*)&Wt[(size_t)n * K + k8 * 8];
    *(uint4*)&wl[n * KP + k8 * 8] = v;
  }
  __syncthreads();

  int lane = tid & 63, w = tid >> 6;
  int m = lane & 15, q = lane >> 4;
  int nf = w & 3;
  int mseg = w >> 2;
  f32x4 acc[MFW];
  #pragma unroll
  for (int i = 0; i < MFW; i++)
    #pragma unroll
    for (int r = 0; r < 4; r++) acc[i][r] = 0.f;

  #pragma unroll
  for (int ks = 0; ks < K / 32; ks++){
    bf16x8 bg = *(const bf16x8*)&wl[(nf * 16 + m) * KP + ks * 32 + q * 8];
    #pragma unroll
    for (int i = 0; i < MFW; i++){
      bf16x8 af = *(const bf16x8*)&xa[((mseg * MFW + i) * 16 + m) * KP + ks * 32 + q * 8];
      acc[i] = __builtin_amdgcn_mfma_f32_16x16x32_bf16(af, bg, acc[i], 0, 0, 0);
    }
  }
  __syncthreads();
  float* C = (float*)smem;
  #pragma unroll
  for (int i = 0; i < MFW; i++)
    #pragma unroll
    for (int r = 0; r < 4; r++)
      C[((mseg * MFW + i) * 16 + q * 4 + r) * CP + nf * 16 + m] = acc[i][r];
  __syncthreads();

  constexpr int CH = NC / 4;   // 16
  int row = tid >> 2;
  int c0 = (tid & 3) * CH;
  int n = n0 + row;
  float s_p = 0.f, d_p = 0.f;
  unsigned short hb[CH];
  #pragma unroll
  for (int c = 0; c < CH; c += 4){
    f32x4 v = *(const f32x4*)&C[row * CP + c0 + c];
    #pragma unroll
    for (int u = 0; u < 4; u++){
      int ch = (c0 + c + u) & 63;
      s_p += v[u] * asrc[ch];
      d_p += v[u] * adst[ch];
      hb[c + u] = f2bf(v[u]);
    }
  }
  if (n < n_rows){
    #pragma unroll
    for (int c = 0; c < CH; c += 8){
      uint4 pk;
      pk.x = (unsigned)hb[c]     | ((unsigned)hb[c + 1] << 16);
      pk.y = (unsigned)hb[c + 2] | ((unsigned)hb[c + 3] << 16);
      pk.z = (unsigned)hb[c + 4] | ((unsigned)hb[c + 5] << 16);
      pk.w = (unsigned)hb[c + 6] | ((unsigned)hb[c + 7] << 16);
      *(uint4*)&Hb[(size_t)n * NC + c0 + c] = pk;
    }
  }
  s_p += __shfl_xor(s_p, 1);
  d_p += __shfl_xor(d_p, 1);
  s_p += __shfl_xor(s_p, 2);
  d_p += __shfl_xor(d_p, 2);
  if ((tid & 3) == 0 && n < n_rows){
    aa[(size_t)n * 2]     = s_p;
    aa[(size_t)n * 2 + 1] = d_p;
  }
}

// ---------- softmax + aggregation (CSR), 2 nodes per wave, deep-MLP gather ----------

__device__ void agg1_one64(int d, int lane, const int* __restrict__ row_ptr,
                           const unsigned* __restrict__ sorted, const float* __restrict__ aa,
                           const unsigned short* __restrict__ h1b, const float* __restrict__ b1,
                           unsigned short* __restrict__ x1b){
  int rp0 = row_ptr[d];
  int deg = row_ptr[d + 1] - rp0;
  float2 adv = *(const float2*)&aa[d * 4 + 2];
  int s = -1;
  if (lane < deg) s = (int)(sorted[rp0 + lane] & 0xffffu);
  else if (lane == deg) s = d;
  float e0 = -INFINITY, e1 = -INFINITY;
  if (s >= 0){
    float2 asv = *(const float2*)&aa[s * 4];
    float t0 = asv.x + adv.x;
    float t1 = asv.y + adv.y;
    e0 = t0 >= 0.f ? t0 : NEG_SLOPE * t0;
    e1 = t1 >= 0.f ? t1 : NEG_SLOPE * t1;
  }
  float m0 = wmax(e0), m1 = wmax(e1);
  float p0 = (s >= 0) ? __expf(e0 - m0) : 0.f;
  float p1 = (s >= 0) ? __expf(e1 - m1) : 0.f;
  float al0 = p0 * __builtin_amdgcn_rcpf(wsum(p0) + 1e-16f);
  float al1 = p1 * __builtin_amdgcn_rcpf(wsum(p1) + 1e-16f);
  int ne = deg + 1;
  int g = lane >> 4, c = lane & 15;
  bool hsel = (c < 8);
  const uint4* hp = (const uint4*)h1b;
  v2f acc[4] = {{0.f,0.f},{0.f,0.f},{0.f,0.f},{0.f,0.f}};
  for (int j0 = 0; j0 < ne; j0 += 16){
    uint4 v[4]; float av[4];
    #pragma unroll
    for (int b = 0; b < 4; b++){
      int j = j0 + b * 4 + g;
      int sj = __shfl(s, j);
      float a0 = __shfl(al0, j);
      float a1 = __shfl(al1, j);
      av[b] = hsel ? a0 : a1;
      if (j < ne) v[b] = hp[(size_t)sj * 16 + c];
    }
    #pragma unroll
    for (int b = 0; b < 4; b++){
      if (j0 + b * 4 + g < ne){
        v2f aw = {av[b], av[b]};
        acc[0] = aw * up2(v[b].x) + acc[0];
        acc[1] = aw * up2(v[b].y) + acc[1];
        acc[2] = aw * up2(v[b].z) + acc[2];
        acc[3] = aw * up2(v[b].w) + acc[3];
      }
    }
  }
  float accf[8] = {acc[0][0], acc[0][1], acc[1][0], acc[1][1],
                   acc[2][0], acc[2][1], acc[3][0], acc[3][1]};
  #pragma unroll
  for (int i = 0; i < 8; i++){
    accf[i] += __shfl_xor(accf[i], 16);
    accf[i] += __shfl_xor(accf[i], 32);
  }
  float outv[8];
  #pragma unroll
  for (int i = 0; i < 8; i++){
    float o = __shfl_xor(accf[i], 8);
    outv[i] = 0.5f * (accf[i] + o);
  }
  if (g == 0 && c < 8){
    unsigned short hb[8];
    #pragma unroll
    for (int i = 0; i < 8; i++){
      float v = outv[i] + b1[c * 8 + i];
      float r = v > 0.f ? v : __expf(v) - 1.0f;
      hb[i] = f2bf(r);
    }
    uint4 pk;
    pk.x = (unsigned)hb[0] | ((unsigned)hb[1] << 16);
    pk.y = (unsigned)hb[2] | ((unsigned)hb[3] << 16);
    pk.z = (unsigned)hb[4] | ((unsigned)hb[5] << 16);
    pk.w = (unsigned)hb[6] | ((unsigned)hb[7] << 16);
    *(uint4*)&x1b[(size_t)d * 64 + c * 8] = pk;
  }
}

__global__ __launch_bounds__(512) void agg_layer1(const int* __restrict__ row_ptr,
    const unsigned* __restrict__ sorted, const float* __restrict__ aa,
    const unsigned short* __restrict__ h1b, const float* __restrict__ b1,
    unsigned short* __restrict__ x1b, int n_nodes, int npair, int nsweep){
  int tid = threadIdx.x;
  int lane = tid & 63;
  if ((int)blockIdx.x >= npair){
    int sw = (blockIdx.x - npair) * 8 + (tid >> 6);
    int chunk = (n_nodes + nsweep - 1) / nsweep;
    int a = sw * chunk;
    int bnd = a + chunk; if (bnd > n_nodes) bnd = n_nodes;
    for (int i0 = a; i0 < bnd; i0 += 64){
      int idx = i0 + lane;
      int dg = 0;
      if (idx < bnd) dg = row_ptr[idx + 1] - row_ptr[idx];
      unsigned long long m = __ballot(dg > 31);
      while (m){
        int bit = __ffsll((long long)m) - 1;
        m &= m - 1;
        agg1_one64(i0 + bit, lane, row_ptr, sorted, aa, h1b, b1, x1b);
      }
    }
    return;
  }
  int wid = (blockIdx.x << 3) + (tid >> 6);
  int half = lane >> 5, l32 = lane & 31;
  int d = wid * 2 + half;
  if (wid * 2 >= n_nodes) return;
  bool valid = d < n_nodes;
  int rp0 = 0, deg = -1;
  if (valid){ rp0 = row_ptr[d]; deg = row_ptr[d + 1] - rp0; }
  bool ok = valid && deg <= 31;
  int ne = ok ? deg + 1 : 0;
  int s = -1;
  if (ok){
    if (l32 < deg) s = (int)(sorted[rp0 + l32] & 0xffffu);
    else if (l32 == deg) s = d;
  }
  float2 adv = make_float2(0.f, 0.f);
  if (valid) adv = *(const float2*)&aa[d * 4 + 2];
  float e0 = -INFINITY, e1 = -INFINITY;
  if (s >= 0){
    float2 asv = *(const float2*)&aa[s * 4];
    float t0 = asv.x + adv.x;
    float t1 = asv.y + adv.y;
    e0 = t0 >= 0.f ? t0 : NEG_SLOPE * t0;
    e1 = t1 >= 0.f ? t1 : NEG_SLOPE * t1;
  }
  float m0 = wmax32(e0), m1 = wmax32(e1);
  float p0 = (s >= 0) ? __expf(e0 - m0) : 0.f;   // unnormalized
  float p1 = (s >= 0) ? __expf(e1 - m1) : 0.f;
  int g = l32 >> 4, c = l32 & 15;
  bool hsel = (c < 8);
  const uint4* hp = (const uint4*)h1b;
  v2f acc[4] = {{0.f,0.f},{0.f,0.f},{0.f,0.f},{0.f,0.f}};
  float dn = 0.f;
  {
    int sj[8]; float pv[8];
    #pragma unroll
    for (int b = 0; b < 8; b++){
      int j = 2 * b + g;
      sj[b] = __shfl(s, j, 32);
      float q0 = __shfl(p0, j, 32);
      float q1 = __shfl(p1, j, 32);
      pv[b] = hsel ? q0 : q1;
    }
    uint4 v[8];
    #pragma unroll
    for (int b = 0; b < 8; b++){
      if (2 * b + g < ne) v[b] = hp[(size_t)sj[b] * 16 + c];
    }
    #pragma unroll
    for (int b = 0; b < 8; b++){
      if (2 * b + g < ne){
        v2f aw = {pv[b], pv[b]};
        acc[0] = aw * up2(v[b].x) + acc[0];
        acc[1] = aw * up2(v[b].y) + acc[1];
        acc[2] = aw * up2(v[b].z) + acc[2];
        acc[3] = aw * up2(v[b].w) + acc[3];
        dn += pv[b];
      }
    }
  }
  if (ne > 16){
    int sj[8]; float pv[8];
    #pragma unroll
    for (int b = 0; b < 8; b++){
      int j = 16 + 2 * b + g;
      sj[b] = __shfl(s, j, 32);
      float q0 = __shfl(p0, j, 32);
      float q1 = __shfl(p1, j, 32);
      pv[b] = hsel ? q0 : q1;
    }
    uint4 v[8];
    #pragma unroll
    for (int b = 0; b < 8; b++){
      if (16 + 2 * b + g < ne) v[b] = hp[(size_t)sj[b] * 16 + c];
    }
    #pragma unroll
    for (int b = 0; b < 8; b++){
      if (16 + 2 * b + g < ne){
        v2f aw = {pv[b], pv[b]};
        acc[0] = aw * up2(v[b].x) + acc[0];
        acc[1] = aw * up2(v[b].y) + acc[1];
        acc[2] = aw * up2(v[b].z) + acc[2];
        acc[3] = aw * up2(v[b].w) + acc[3];
        dn += pv[b];
      }
    }
  }
  float accf[8] = {acc[0][0], acc[0][1], acc[1][0], acc[1][1],
                   acc[2][0], acc[2][1], acc[3][0], acc[3][1]};
  #pragma unroll
  for (int i = 0; i < 8; i++) accf[i] += __shfl_xor(accf[i], 16, 32);
  dn += __shfl_xor(dn, 16, 32);
  float inv = __builtin_amdgcn_rcpf(dn);   // dn >= 1 (self-loop) when ok
  float outv[8];
  #pragma unroll
  for (int i = 0; i < 8; i++){
    float r = accf[i] * inv;
    float o = __shfl_xor(r, 8, 32);
    outv[i] = 0.5f * (r + o);
  }
  if (ok && l32 < 8){
    unsigned short hb[8];
    #pragma unroll
    for (int i = 0; i < 8; i++){
      float v = outv[i] + b1[l32 * 8 + i];
      float r = v > 0.f ? v : __expf(v) - 1.0f;
      hb[i] = f2bf(r);
    }
    uint4 pk;
    pk.x = (unsigned)hb[0] | ((unsigned)hb[1] << 16);
    pk.y = (unsigned)hb[2] | ((unsigned)hb[3] << 16);
    pk.z = (unsigned)hb[4] | ((unsigned)hb[5] << 16);
    pk.w = (unsigned)hb[6] | ((unsigned)hb[7] << 16);
    *(uint4*)&x1b[(size_t)d * 64 + l32 * 8] = pk;
  }
}

__device__ void agg2_one64(int d, int lane, const int* __restrict__ row_ptr,
                           const unsigned* __restrict__ sorted, const float* __restrict__ aa,
                           const unsigned short* __restrict__ h2b, const float* __restrict__ b2,
                           float* __restrict__ out){
  int rp0 = row_ptr[d];
  int deg = row_ptr[d + 1] - rp0;
  float ad = aa[d * 2 + 1];
  int s = -1;
  if (lane < deg) s = (int)(sorted[rp0 + lane] & 0xffffu);
  else if (lane == deg) s = d;
  float e = -INFINITY;
  if (s >= 0){
    float t = aa[s * 2 + 0] + ad;
    e = t >= 0.f ? t : NEG_SLOPE * t;
  }
  float m = wmax(e);
  float p = (s >= 0) ? __expf(e - m) : 0.f;
  float al = p * __builtin_amdgcn_rcpf(wsum(p) + 1e-16f);
  int ne = deg + 1;
  int g = lane >> 3, c = lane & 7;
  const uint4* hp = (const uint4*)h2b;
  v2f acc[4] = {{0.f,0.f},{0.f,0.f},{0.f,0.f},{0.f,0.f}};
  for (int j0 = 0; j0 < ne; j0 += 32){
    uint4 v[4]; float av[4];
    #pragma unroll
    for (int b = 0; b < 4; b++){
      int j = j0 + b * 8 + g;
      int sj = __shfl(s, j);
      av[b] = __shfl(al, j);
      if (j < ne) v[b] = hp[(size_t)sj * 8 + c];
    }
    #pragma unroll
    for (int b = 0; b < 4; b++){
      if (j0 + b * 8 + g < ne){
        v2f aw = {av[b], av[b]};
        acc[0] = aw * up2(v[b].x) + acc[0];
        acc[1] = aw * up2(v[b].y) + acc[1];
        acc[2] = aw * up2(v[b].z) + acc[2];
        acc[3] = aw * up2(v[b].w) + acc[3];
      }
    }
  }
  float accf[8] = {acc[0][0], acc[0][1], acc[1][0], acc[1][1],
                   acc[2][0], acc[2][1], acc[3][0], acc[3][1]};
  #pragma unroll
  for (int i = 0; i < 8; i++){
    accf[i] += __shfl_xor(accf[i], 8);
    accf[i] += __shfl_xor(accf[i], 16);
    accf[i] += __shfl_xor(accf[i], 32);
  }
  if (lane < 8){
    float r[8];
    #pragma unroll
    for (int i = 0; i < 8; i++) r[i] = accf[i] + b2[lane * 8 + i];
    float* q = &out[(size_t)d * 64 + lane * 8];
    *(float4*)q       = make_float4(r[0], r[1], r[2], r[3]);
    *(float4*)(q + 4) = make_float4(r[4], r[5], r[6], r[7]);
  }
}

__global__ __launch_bounds__(512) void agg_layer2(const int* __restrict__ row_ptr,
    const unsigned* __restrict__ sorted, const float* __restrict__ aa,
    const unsigned short* __restrict__ h2b, const float* __restrict__ b2,
    float* __restrict__ out, int n_nodes, int npair, int nsweep){
  int tid = threadIdx.x;
  int lane = tid & 63;
  if ((int)blockIdx.x >= npair){
    int sw = (blockIdx.x - npair) * 8 + (tid >> 6);
    int chunk = (n_nodes + nsweep - 1) / nsweep;
    int a = sw * chunk;
    int bnd = a + chunk; if (bnd > n_nodes) bnd = n_nodes;
    for (int i0 = a; i0 < bnd; i0 += 64){
      int idx = i0 + lane;
      int dg = 0;
      if (idx < bnd) dg = row_ptr[idx + 1] - row_ptr[idx];
      unsigned long long m = __ballot(dg > 31);
      while (m){
        int bit = __ffsll((long long)m) - 1;
        m &= m - 1;
        agg2_one64(i0 + bit, lane, row_ptr, sorted, aa, h2b, b2, out);
      }
    }
    return;
  }
  int wid = (blockIdx.x << 3) + (tid >> 6);
  int half = lane >> 5, l32 = lane & 31;
  int d = wid * 2 + half;
  if (wid * 2 >= n_nodes) return;
  bool valid = d < n_nodes;
  int rp0 = 0, deg = -1;
  if (valid){ rp0 = row_ptr[d]; deg = row_ptr[d + 1] - rp0; }
  bool ok = valid && deg <= 31;
  int ne = ok ? deg + 1 : 0;
  int s = -1;
  if (ok){
    if (l32 < deg) s = (int)(sorted[rp0 + l32] & 0xffffu);
    else if (l32 == deg) s = d;
  }
  float ad = valid ? aa[d * 2 + 1] : 0.f;
  float e = -INFINITY;
  if (s >= 0){
    float t = aa[s * 2 + 0] + ad;
    e = t >= 0.f ? t : NEG_SLOPE * t;
  }
  float m = wmax32(e);
  float p = (s >= 0) ? __expf(e - m) : 0.f;   // unnormalized
  int g = l32 >> 3, c = l32 & 7;
  const uint4* hp = (const uint4*)h2b;
  v2f acc[4] = {{0.f,0.f},{0.f,0.f},{0.f,0.f},{0.f,0.f}};
  float dn = 0.f;
  {
    int sj[8]; float pv[8];
    #pragma unroll
    for (int b = 0; b < 8; b++){
      int j = 4 * b + g;
      sj[b] = __shfl(s, j, 32);
      pv[b] = __shfl(p, j, 32);
    }
    uint4 v[8];
    #pragma unroll
    for (int b = 0; b < 8; b++){
      if (4 * b + g < ne) v[b] = hp[(size_t)sj[b] * 8 + c];
    }
    #pragma unroll
    for (int b = 0; b < 8; b++){
      if (4 * b + g < ne){
        v2f aw = {pv[b], pv[b]};
        acc[0] = aw * up2(v[b].x) + acc[0];
        acc[1] = aw * up2(v[b].y) + acc[1];
        acc[2] = aw * up2(v[b].z) + acc[2];
        acc[3] = aw * up2(v[b].w) + acc[3];
        dn += pv[b];
      }
    }
  }
  float accf[8] = {acc[0][0], acc[0][1], acc[1][0], acc[1][1],
                   acc[2][0], acc[2][1], acc[3][0], acc[3][1]};
  #pragma unroll
  for (int i = 0; i < 8; i++){
    accf[i] += __shfl_xor(accf[i], 8, 32);
    accf[i] += __shfl_xor(accf[i], 16, 32);
  }
  dn += __shfl_xor(dn, 8, 32);
  dn += __shfl_xor(dn, 16, 32);
  float inv = __builtin_amdgcn_rcpf(dn);   // dn >= 1 (self-loop) when ok
  if (ok && l32 < 8){
    float r[8];
    #pragma unroll
    for (int i = 0; i < 8; i++) r[i] = accf[i] * inv + b2[l32 * 8 + i];
    float* q = &out[(size_t)d * 64 + l32 * 8];
    *(float4*)q       = make_float4(r[0], r[1], r[2], r[3]);
    *(float4*)(q + 4) = make_float4(r[4], r[5], r[6], r[7]);
  }
}

extern "C" void kernel_launch(void* const* d_in, const int* in_sizes, int n_in,
                              void* d_out, int out_size, void* d_ws, size_t ws_size,
                              hipStream_t stream){
  const float* x     = (const float*)d_in[0];
  const int*   ei    = (const int*)d_in[1];
  const float* W1    = (const float*)d_in[2];
  const float* asrc1 = (const float*)d_in[3];
  const float* adst1 = (const float*)d_in[4];
  const float* b1    = (const float*)d_in[5];
  const float* W2    = (const float*)d_in[6];
  const float* asrc2 = (const float*)d_in[7];
  const float* adst2 = (const float*)d_in[8];
  const float* b2    = (const float*)d_in[9];
  float* out = (float*)d_out;
  int N = in_sizes[0] / IN_DIM;   // 50000 (< 65536 for 16-bit packing)
  int E = in_sizes[1] / 2;
  int NBLK = (E + CHUNK - 1) / CHUNK;       // edge chunks (196)
  int npair = (N + 15) / 16;                // 2 nodes/wave, 8 waves/block
  int GT = (N + 63) / 64;                   // gemm1 blocks (782)

  char* p = (char*)d_ws;
  unsigned short* h1b = (unsigned short*)p;  p += (size_t)N * 128 * 2;
  unsigned short* h2b = (unsigned short*)p;  p += (size_t)N * 64 * 2;
  unsigned short* x1b = (unsigned short*)p;  p += (size_t)N * 64 * 2;
  float* aa1 = (float*)p;                    p += (size_t)N * 4 * 4;
  float* aa2 = (float*)p;                    p += (size_t)N * 2 * 4;
  unsigned* sorted = (unsigned*)p;           p += (size_t)E * 4;
  int* row_ptr   = (int*)p;                  p += (size_t)(N + 1) * 4;
  int* deg       = (int*)p;                  p += (size_t)N * 4;
  int* cur       = (int*)p;                  p += (size_t)N * 4;
  unsigned short* W1t = (unsigned short*)p;  p += 128 * 128 * 2;
  unsigned short* W2t = (unsigned short*)p;

  hipMemsetAsync(deg, 0, (size_t)N * sizeof(int), stream);
  prep<<<NBLK + 80, 256, 0, stream>>>(ei, E, NBLK, deg, W1, W2, W1t, W2t);
  scan_seed<<<1, 1024, 0, stream>>>(deg, row_ptr, cur, N, E);
  scatter_gemm<<<NBLK + GT, 256, 0, stream>>>(ei, E, cur, sorted, NBLK,
                                              x, W1t, asrc1, adst1, h1b, aa1, N);
  agg_layer1<<<npair + NBIGBLK, 512, 0, stream>>>(row_ptr, sorted, aa1, h1b, b1, x1b,
                                                  N, npair, NBIGBLK * 8);
  gemm2_mfma<<<(N + 127) / 128, 512, 0, stream>>>(x1b, W2t, asrc2, adst2, h2b, aa2, N);
  agg_layer2<<<npair + NBIGBLK, 512, 0, stream>>>(row_ptr, sorted, aa2, h2b, b2, out,
                                                  N, npair, NBIGBLK * 8);
}

// Round 6
// 247.411 us; speedup vs baseline: 1.3868x; 1.3868x over previous
//
#include <hip/hip_runtime.h>
#include <math.h>

#define IN_DIM 128
#define HID 64
#define NEG_SLOPE 0.2f
#define CHUNK 4096
#define SMEM_UNION 53248
#define NBIGBLK 40

typedef __attribute__((ext_vector_type(8))) short bf16x8;
typedef __attribute__((ext_vector_type(4))) float f32x4;
typedef __attribute__((ext_vector_type(2))) float v2f;

__device__ __forceinline__ float wmax(float v){
  #pragma unroll
  for (int o = 32; o > 0; o >>= 1) v = fmaxf(v, __shfl_xor(v, o));
  return v;
}
__device__ __forceinline__ float wsum(float v){
  #pragma unroll
  for (int o = 32; o > 0; o >>= 1) v += __shfl_xor(v, o);
  return v;
}
__device__ __forceinline__ float wmax32(float v){
  #pragma unroll
  for (int o = 16; o > 0; o >>= 1) v = fmaxf(v, __shfl_xor(v, o, 32));
  return v;
}
__device__ __forceinline__ unsigned short f2bf(float f){
  union { float f; unsigned u; } v; v.f = f;
  unsigned r = v.u + 0x7fffu + ((v.u >> 16) & 1u);
  return (unsigned short)(r >> 16);
}
__device__ __forceinline__ float bl(unsigned u){
  union { unsigned u; float f; } v; v.u = u << 16; return v.f;
}
__device__ __forceinline__ float bh(unsigned u){
  union { unsigned u; float f; } v; v.u = u & 0xffff0000u; return v.f;
}
__device__ __forceinline__ v2f up2(unsigned u){
  v2f r; r[0] = bl(u); r[1] = bh(u); return r;
}

// ---------- CSR build: counting sort, scan-free base assignment ----------
// R5 lesson: a single-block serial scan (110us, 1 CU busy) was the bubble.
// CSR consumers never need monotonic row_ptr -- only per-node (base, deg),
// and deg[] is its own array. So bases are assigned order-free: wave prefix
// scan of deg + LDS combine + ONE atomicAdd(counter) per 1024-node block
// (49 atomics total). Fully parallel, ~5us.

__global__ __launch_bounds__(256) void prep(const int* __restrict__ ei, int E, int NBLK,
                                            int* __restrict__ deg,
                                            const float* __restrict__ W1,
                                            const float* __restrict__ W2,
                                            unsigned short* __restrict__ W1t,
                                            unsigned short* __restrict__ W2t){
  int tid = threadIdx.x;
  if ((int)blockIdx.x < NBLK){
    int base = blockIdx.x * CHUNK;
    if (((E & 3) == 0) && (base + CHUNK <= E)){
      // vectorized: 4 consecutive dsts per thread, coalesced int4 loads
      #pragma unroll
      for (int j = 0; j < 4; j++){
        int e0 = base + j * 1024 + tid * 4;
        int4 dv = *(const int4*)&ei[E + e0];
        atomicAdd(&deg[dv.x], 1);
        atomicAdd(&deg[dv.y], 1);
        atomicAdd(&deg[dv.z], 1);
        atomicAdd(&deg[dv.w], 1);
      }
    } else {
      #pragma unroll
      for (int j = 0; j < CHUNK / 256; j++){
        int e = base + j * 256 + tid;
        if (e < E) atomicAdd(&deg[ei[E + e]], 1);
      }
    }
  } else {
    int t = (blockIdx.x - NBLK) * 256 + tid;
    if (t < 128 * 128){
      int n = t >> 7, k = t & 127;
      W1t[n * 128 + k] = f2bf(W1[k * 128 + n]);
    }
    int t2 = t - 128 * 128;
    if (t2 >= 0 && t2 < 64 * 64){
      int n = t2 >> 6, k = t2 & 63;
      W2t[n * 64 + k] = f2bf(W2[k * 64 + n]);
    }
  }
}

// parallel base assignment: 1024 nodes/block, wave scan + 1 atomic per block
__global__ __launch_bounds__(1024) void base_assign(const int* __restrict__ deg,
    int* __restrict__ row_ptr, int* __restrict__ cur, int* __restrict__ counter, int N){
  __shared__ int wsum[16];
  __shared__ int bbase;
  int tid = threadIdx.x;
  int i = blockIdx.x * 1024 + tid;
  int lane = tid & 63, wid = tid >> 6;
  int dg = (i < N) ? deg[i] : 0;
  int sc = dg;
  #pragma unroll
  for (int o = 1; o < 64; o <<= 1){
    int t = __shfl_up(sc, o);
    if (lane >= o) sc += t;
  }
  if (lane == 63) wsum[wid] = sc;
  __syncthreads();
  if (tid == 0){
    int run = 0;
    #pragma unroll
    for (int w = 0; w < 16; w++){ int t = wsum[w]; wsum[w] = run; run += t; }
    bbase = atomicAdd(counter, run);
  }
  __syncthreads();
  if (i < N){
    int b = bbase + wsum[wid] + sc - dg;
    row_ptr[i] = b;
    cur[i] = b;
  }
}

__device__ void scatter_direct(const int* __restrict__ ei, int E, int* __restrict__ cur,
                               unsigned* __restrict__ sorted, int bx){
  int base = bx * CHUNK;
  int tid = threadIdx.x;
  if (((E & 3) == 0) && (base + CHUNK <= E)){
    #pragma unroll
    for (int j = 0; j < 4; j++){
      int e0 = base + j * 1024 + tid * 4;
      int4 sv = *(const int4*)&ei[e0];
      int4 dv = *(const int4*)&ei[E + e0];
      int p0 = atomicAdd(&cur[dv.x], 1);
      int p1 = atomicAdd(&cur[dv.y], 1);
      int p2 = atomicAdd(&cur[dv.z], 1);
      int p3 = atomicAdd(&cur[dv.w], 1);
      sorted[p0] = (unsigned)sv.x;
      sorted[p1] = (unsigned)sv.y;
      sorted[p2] = (unsigned)sv.z;
      sorted[p3] = (unsigned)sv.w;
    }
  } else {
    #pragma unroll
    for (int j = 0; j < CHUNK / 256; j++){
      int e = base + j * 256 + tid;
      if (e < E){
        int pos = atomicAdd(&cur[ei[E + e]], 1);
        sorted[pos] = (unsigned)ei[e];
      }
    }
  }
}

// ---------- layer-1 GEMM body (MT=64, K=128, NC=128, 2 heads, 256 threads) ----------

__device__ void gemm1_body(char* smem, const float* __restrict__ X,
                           const unsigned short* __restrict__ Wt,
                           const float* __restrict__ asrc, const float* __restrict__ adst,
                           unsigned short* __restrict__ Hb, float* __restrict__ aa,
                           int n_rows, int n0){
  const int KP = 136, CP = 132;
  unsigned short* xa = (unsigned short*)smem;   // [64][136]
  unsigned short* wl = xa + 64 * KP;            // [128][136]
  int tid = threadIdx.x;
  for (int idx = tid; idx < 64 * 32; idx += 256){
    int n = idx >> 5, k4 = idx & 31;
    float4 v = make_float4(0.f, 0.f, 0.f, 0.f);
    if (n0 + n < n_rows) v = *(const float4*)&X[(size_t)(n0 + n) * 128 + k4 * 4];
    ushort4 pk; pk.x = f2bf(v.x); pk.y = f2bf(v.y); pk.z = f2bf(v.z); pk.w = f2bf(v.w);
    *(ushort4*)&xa[n * KP + k4 * 4] = pk;
  }
  for (int idx = tid; idx < 128 * 16; idx += 256){
    int n = idx >> 4, k8 = idx & 15;
    uint4 v = *(const uint4*)&Wt[(size_t)n * 128 + k8 * 8];
    *(uint4*)&wl[n * KP + k8 * 8] = v;
  }
  __syncthreads();

  int lane = tid & 63, w = tid >> 6;
  int m = lane & 15, q = lane >> 4;
  f32x4 acc[4][2];
  #pragma unroll
  for (int i = 0; i < 4; i++)
    #pragma unroll
    for (int j = 0; j < 2; j++)
      #pragma unroll
      for (int r = 0; r < 4; r++) acc[i][j][r] = 0.f;
  #pragma unroll
  for (int ks = 0; ks < 4; ks++){
    bf16x8 bg[2];
    #pragma unroll
    for (int j = 0; j < 2; j++)
      bg[j] = *(const bf16x8*)&wl[((2 * w + j) * 16 + m) * KP + ks * 32 + q * 8];
    #pragma unroll
    for (int i = 0; i < 4; i++){
      bf16x8 af = *(const bf16x8*)&xa[(i * 16 + m) * KP + ks * 32 + q * 8];
      #pragma unroll
      for (int j = 0; j < 2; j++)
        acc[i][j] = __builtin_amdgcn_mfma_f32_16x16x32_bf16(af, bg[j], acc[i][j], 0, 0, 0);
    }
  }
  __syncthreads();
  float* C = (float*)smem;   // [64][132]
  #pragma unroll
  for (int i = 0; i < 4; i++)
    #pragma unroll
    for (int j = 0; j < 2; j++)
      #pragma unroll
      for (int r = 0; r < 4; r++)
        C[(i * 16 + q * 4 + r) * CP + (2 * w + j) * 16 + m] = acc[i][j][r];
  __syncthreads();

  int row = tid >> 2;
  int c0 = (tid & 3) * 32;
  int n = n0 + row;
  int head = (tid & 3) >> 1;
  float s_p = 0.f, d_p = 0.f;
  unsigned short hb[32];
  #pragma unroll
  for (int c = 0; c < 32; c += 4){
    f32x4 v = *(const f32x4*)&C[row * CP + c0 + c];
    #pragma unroll
    for (int u = 0; u < 4; u++){
      int ch = (c0 + c + u) & 63;
      s_p += v[u] * asrc[head * 64 + ch];
      d_p += v[u] * adst[head * 64 + ch];
      hb[c + u] = f2bf(v[u]);
    }
  }
  if (n < n_rows){
    #pragma unroll
    for (int c = 0; c < 32; c += 8){
      uint4 pk;
      pk.x = (unsigned)hb[c]     | ((unsigned)hb[c + 1] << 16);
      pk.y = (unsigned)hb[c + 2] | ((unsigned)hb[c + 3] << 16);
      pk.z = (unsigned)hb[c + 4] | ((unsigned)hb[c + 5] << 16);
      pk.w = (unsigned)hb[c + 6] | ((unsigned)hb[c + 7] << 16);
      *(uint4*)&Hb[(size_t)n * 128 + c0 + c] = pk;
    }
  }
  s_p += __shfl_xor(s_p, 1);
  d_p += __shfl_xor(d_p, 1);
  if ((tid & 1) == 0 && n < n_rows){
    aa[(size_t)n * 4 + head]     = s_p;
    aa[(size_t)n * 4 + 2 + head] = d_p;
  }
}

// combined: scatter blocks + gemm1 blocks in one launch
__global__ __launch_bounds__(256) void scatter_gemm(const int* __restrict__ ei, int E,
    int* __restrict__ cur, unsigned* __restrict__ sorted, int NS,
    const float* __restrict__ X, const unsigned short* __restrict__ W1t,
    const float* __restrict__ asrc1, const float* __restrict__ adst1,
    unsigned short* __restrict__ h1b, float* __restrict__ aa1, int n_rows){
  __shared__ char smem[SMEM_UNION];
  int bx = blockIdx.x;
  if (bx < NS){
    scatter_direct(ei, E, cur, sorted, bx);
  } else {
    gemm1_body(smem, X, W1t, asrc1, adst1, h1b, aa1, n_rows, (bx - NS) * 64);
  }
}

// ---------- layer-2 GEMM (bf16 input x1b, M-tile 128, 512 threads) ----------

__global__ __launch_bounds__(512) void gemm2_mfma(const unsigned short* __restrict__ Xb,
    const unsigned short* __restrict__ Wt, const float* __restrict__ asrc,
    const float* __restrict__ adst, unsigned short* __restrict__ Hb,
    float* __restrict__ aa, int n_rows)
{
  constexpr int K = 64, NC = 64;
  constexpr int MT = 128;
  constexpr int KP = K + 8;
  constexpr int CP = NC + 4;
  constexpr int MFW = 4;
  constexpr unsigned SM1 = (unsigned)(MT + NC) * KP * 2;
  constexpr unsigned SM2 = (unsigned)MT * CP * 4;
  __shared__ char smem[SM1 > SM2 ? SM1 : SM2];
  unsigned short* xa = (unsigned short*)smem;
  unsigned short* wl = xa + MT * KP;
  int tid = threadIdx.x;
  int n0 = blockIdx.x * MT;

  for (int idx = tid; idx < MT * (K / 8); idx += 512){
    int n = idx >> 3, k8 = idx & 7;
    uint4 v = make_uint4(0u, 0u, 0u, 0u);
    if (n0 + n < n_rows) v = *(const uint4*)&Xb[(size_t)(n0 + n) * K + k8 * 8];
    *(uint4*)&xa[n * KP + k8 * 8] = v;
  }
  for (int idx = tid; idx < NC * (K / 8); idx += 512){
    int n = idx >> 3, k8 = idx & 7;
    uint4 v = *(const uint4*)&Wt[(size_t)n * K + k8 * 8];
    *(uint4*)&wl[n * KP + k8 * 8] = v;
  }
  __syncthreads();

  int lane = tid & 63, w = tid >> 6;
  int m = lane & 15, q = lane >> 4;
  int nf = w & 3;
  int mseg = w >> 2;
  f32x4 acc[MFW];
  #pragma unroll
  for (int i = 0; i < MFW; i++)
    #pragma unroll
    for (int r = 0; r < 4; r++) acc[i][r] = 0.f;

  #pragma unroll
  for (int ks = 0; ks < K / 32; ks++){
    bf16x8 bg = *(const bf16x8*)&wl[(nf * 16 + m) * KP + ks * 32 + q * 8];
    #pragma unroll
    for (int i = 0; i < MFW; i++){
      bf16x8 af = *(const bf16x8*)&xa[((mseg * MFW + i) * 16 + m) * KP + ks * 32 + q * 8];
      acc[i] = __builtin_amdgcn_mfma_f32_16x16x32_bf16(af, bg, acc[i], 0, 0, 0);
    }
  }
  __syncthreads();
  float* C = (float*)smem;
  #pragma unroll
  for (int i = 0; i < MFW; i++)
    #pragma unroll
    for (int r = 0; r < 4; r++)
      C[((mseg * MFW + i) * 16 + q * 4 + r) * CP + nf * 16 + m] = acc[i][r];
  __syncthreads();

  constexpr int CH = NC / 4;   // 16
  int row = tid >> 2;
  int c0 = (tid & 3) * CH;
  int n = n0 + row;
  float s_p = 0.f, d_p = 0.f;
  unsigned short hb[CH];
  #pragma unroll
  for (int c = 0; c < CH; c += 4){
    f32x4 v = *(const f32x4*)&C[row * CP + c0 + c];
    #pragma unroll
    for (int u = 0; u < 4; u++){
      int ch = (c0 + c + u) & 63;
      s_p += v[u] * asrc[ch];
      d_p += v[u] * adst[ch];
      hb[c + u] = f2bf(v[u]);
    }
  }
  if (n < n_rows){
    #pragma unroll
    for (int c = 0; c < CH; c += 8){
      uint4 pk;
      pk.x = (unsigned)hb[c]     | ((unsigned)hb[c + 1] << 16);
      pk.y = (unsigned)hb[c + 2] | ((unsigned)hb[c + 3] << 16);
      pk.z = (unsigned)hb[c + 4] | ((unsigned)hb[c + 5] << 16);
      pk.w = (unsigned)hb[c + 6] | ((unsigned)hb[c + 7] << 16);
      *(uint4*)&Hb[(size_t)n * NC + c0 + c] = pk;
    }
  }
  s_p += __shfl_xor(s_p, 1);
  d_p += __shfl_xor(d_p, 1);
  s_p += __shfl_xor(s_p, 2);
  d_p += __shfl_xor(d_p, 2);
  if ((tid & 3) == 0 && n < n_rows){
    aa[(size_t)n * 2]     = s_p;
    aa[(size_t)n * 2 + 1] = d_p;
  }
}

// ---------- softmax + aggregation (CSR via base+deg arrays) ----------

__device__ void agg1_one64(int d, int lane, const int* __restrict__ row_ptr,
                           const int* __restrict__ degarr,
                           const unsigned* __restrict__ sorted, const float* __restrict__ aa,
                           const unsigned short* __restrict__ h1b, const float* __restrict__ b1,
                           unsigned short* __restrict__ x1b){
  int rp0 = row_ptr[d];
  int deg = degarr[d];
  float2 adv = *(const float2*)&aa[d * 4 + 2];
  int s = -1;
  if (lane < deg) s = (int)(sorted[rp0 + lane] & 0xffffu);
  else if (lane == deg) s = d;
  float e0 = -INFINITY, e1 = -INFINITY;
  if (s >= 0){
    float2 asv = *(const float2*)&aa[s * 4];
    float t0 = asv.x + adv.x;
    float t1 = asv.y + adv.y;
    e0 = t0 >= 0.f ? t0 : NEG_SLOPE * t0;
    e1 = t1 >= 0.f ? t1 : NEG_SLOPE * t1;
  }
  float m0 = wmax(e0), m1 = wmax(e1);
  float p0 = (s >= 0) ? __expf(e0 - m0) : 0.f;
  float p1 = (s >= 0) ? __expf(e1 - m1) : 0.f;
  float al0 = p0 * __builtin_amdgcn_rcpf(wsum(p0) + 1e-16f);
  float al1 = p1 * __builtin_amdgcn_rcpf(wsum(p1) + 1e-16f);
  int ne = deg + 1;
  int g = lane >> 4, c = lane & 15;
  bool hsel = (c < 8);
  const uint4* hp = (const uint4*)h1b;
  v2f acc[4] = {{0.f,0.f},{0.f,0.f},{0.f,0.f},{0.f,0.f}};
  for (int j0 = 0; j0 < ne; j0 += 16){
    uint4 v[4]; float av[4];
    #pragma unroll
    for (int b = 0; b < 4; b++){
      int j = j0 + b * 4 + g;
      int sj = __shfl(s, j);
      float a0 = __shfl(al0, j);
      float a1 = __shfl(al1, j);
      av[b] = hsel ? a0 : a1;
      if (j < ne) v[b] = hp[(size_t)sj * 16 + c];
    }
    #pragma unroll
    for (int b = 0; b < 4; b++){
      if (j0 + b * 4 + g < ne){
        v2f aw = {av[b], av[b]};
        acc[0] = aw * up2(v[b].x) + acc[0];
        acc[1] = aw * up2(v[b].y) + acc[1];
        acc[2] = aw * up2(v[b].z) + acc[2];
        acc[3] = aw * up2(v[b].w) + acc[3];
      }
    }
  }
  float accf[8] = {acc[0][0], acc[0][1], acc[1][0], acc[1][1],
                   acc[2][0], acc[2][1], acc[3][0], acc[3][1]};
  #pragma unroll
  for (int i = 0; i < 8; i++){
    accf[i] += __shfl_xor(accf[i], 16);
    accf[i] += __shfl_xor(accf[i], 32);
  }
  float outv[8];
  #pragma unroll
  for (int i = 0; i < 8; i++){
    float o = __shfl_xor(accf[i], 8);
    outv[i] = 0.5f * (accf[i] + o);
  }
  if (g == 0 && c < 8){
    unsigned short hb[8];
    #pragma unroll
    for (int i = 0; i < 8; i++){
      float v = outv[i] + b1[c * 8 + i];
      float r = v > 0.f ? v : __expf(v) - 1.0f;
      hb[i] = f2bf(r);
    }
    uint4 pk;
    pk.x = (unsigned)hb[0] | ((unsigned)hb[1] << 16);
    pk.y = (unsigned)hb[2] | ((unsigned)hb[3] << 16);
    pk.z = (unsigned)hb[4] | ((unsigned)hb[5] << 16);
    pk.w = (unsigned)hb[6] | ((unsigned)hb[7] << 16);
    *(uint4*)&x1b[(size_t)d * 64 + c * 8] = pk;
  }
}

__global__ __launch_bounds__(512) void agg_layer1(const int* __restrict__ row_ptr,
    const int* __restrict__ degarr,
    const unsigned* __restrict__ sorted, const float* __restrict__ aa,
    const unsigned short* __restrict__ h1b, const float* __restrict__ b1,
    unsigned short* __restrict__ x1b, int n_nodes, int npair, int nsweep){
  int tid = threadIdx.x;
  int lane = tid & 63;
  if ((int)blockIdx.x >= npair){
    int sw = (blockIdx.x - npair) * 8 + (tid >> 6);
    int chunk = (n_nodes + nsweep - 1) / nsweep;
    int a = sw * chunk;
    int bnd = a + chunk; if (bnd > n_nodes) bnd = n_nodes;
    for (int i0 = a; i0 < bnd; i0 += 64){
      int idx = i0 + lane;
      int dg = 0;
      if (idx < bnd) dg = degarr[idx];
      unsigned long long m = __ballot(dg > 31);
      while (m){
        int bit = __ffsll((long long)m) - 1;
        m &= m - 1;
        agg1_one64(i0 + bit, lane, row_ptr, degarr, sorted, aa, h1b, b1, x1b);
      }
    }
    return;
  }
  int wid = (blockIdx.x << 3) + (tid >> 6);
  int half = lane >> 5, l32 = lane & 31;
  int d = wid * 2 + half;
  if (wid * 2 >= n_nodes) return;
  bool valid = d < n_nodes;
  int rp0 = 0, deg = -1;
  if (valid){ rp0 = row_ptr[d]; deg = degarr[d]; }
  bool ok = valid && deg <= 31;
  int ne = ok ? deg + 1 : 0;
  int s = -1;
  if (ok){
    if (l32 < deg) s = (int)(sorted[rp0 + l32] & 0xffffu);
    else if (l32 == deg) s = d;
  }
  float2 adv = make_float2(0.f, 0.f);
  if (valid) adv = *(const float2*)&aa[d * 4 + 2];
  float e0 = -INFINITY, e1 = -INFINITY;
  if (s >= 0){
    float2 asv = *(const float2*)&aa[s * 4];
    float t0 = asv.x + adv.x;
    float t1 = asv.y + adv.y;
    e0 = t0 >= 0.f ? t0 : NEG_SLOPE * t0;
    e1 = t1 >= 0.f ? t1 : NEG_SLOPE * t1;
  }
  float m0 = wmax32(e0), m1 = wmax32(e1);
  float p0 = (s >= 0) ? __expf(e0 - m0) : 0.f;   // unnormalized
  float p1 = (s >= 0) ? __expf(e1 - m1) : 0.f;
  int g = l32 >> 4, c = l32 & 15;
  bool hsel = (c < 8);
  const uint4* hp = (const uint4*)h1b;
  v2f acc[4] = {{0.f,0.f},{0.f,0.f},{0.f,0.f},{0.f,0.f}};
  float dn = 0.f;
  {
    int sj[8]; float pv[8];
    #pragma unroll
    for (int b = 0; b < 8; b++){
      int j = 2 * b + g;
      sj[b] = __shfl(s, j, 32);
      float q0 = __shfl(p0, j, 32);
      float q1 = __shfl(p1, j, 32);
      pv[b] = hsel ? q0 : q1;
    }
    uint4 v[8];
    #pragma unroll
    for (int b = 0; b < 8; b++){
      if (2 * b + g < ne) v[b] = hp[(size_t)sj[b] * 16 + c];
    }
    #pragma unroll
    for (int b = 0; b < 8; b++){
      if (2 * b + g < ne){
        v2f aw = {pv[b], pv[b]};
        acc[0] = aw * up2(v[b].x) + acc[0];
        acc[1] = aw * up2(v[b].y) + acc[1];
        acc[2] = aw * up2(v[b].z) + acc[2];
        acc[3] = aw * up2(v[b].w) + acc[3];
        dn += pv[b];
      }
    }
  }
  if (ne > 16){
    int sj[8]; float pv[8];
    #pragma unroll
    for (int b = 0; b < 8; b++){
      int j = 16 + 2 * b + g;
      sj[b] = __shfl(s, j, 32);
      float q0 = __shfl(p0, j, 32);
      float q1 = __shfl(p1, j, 32);
      pv[b] = hsel ? q0 : q1;
    }
    uint4 v[8];
    #pragma unroll
    for (int b = 0; b < 8; b++){
      if (16 + 2 * b + g < ne) v[b] = hp[(size_t)sj[b] * 16 + c];
    }
    #pragma unroll
    for (int b = 0; b < 8; b++){
      if (16 + 2 * b + g < ne){
        v2f aw = {pv[b], pv[b]};
        acc[0] = aw * up2(v[b].x) + acc[0];
        acc[1] = aw * up2(v[b].y) + acc[1];
        acc[2] = aw * up2(v[b].z) + acc[2];
        acc[3] = aw * up2(v[b].w) + acc[3];
        dn += pv[b];
      }
    }
  }
  float accf[8] = {acc[0][0], acc[0][1], acc[1][0], acc[1][1],
                   acc[2][0], acc[2][1], acc[3][0], acc[3][1]};
  #pragma unroll
  for (int i = 0; i < 8; i++) accf[i] += __shfl_xor(accf[i], 16, 32);
  dn += __shfl_xor(dn, 16, 32);
  float inv = __builtin_amdgcn_rcpf(dn);   // dn >= 1 (self-loop) when ok
  float outv[8];
  #pragma unroll
  for (int i = 0; i < 8; i++){
    float r = accf[i] * inv;
    float o = __shfl_xor(r, 8, 32);
    outv[i] = 0.5f * (r + o);
  }
  if (ok && l32 < 8){
    unsigned short hb[8];
    #pragma unroll
    for (int i = 0; i < 8; i++){
      float v = outv[i] + b1[l32 * 8 + i];
      float r = v > 0.f ? v : __expf(v) - 1.0f;
      hb[i] = f2bf(r);
    }
    uint4 pk;
    pk.x = (unsigned)hb[0] | ((unsigned)hb[1] << 16);
    pk.y = (unsigned)hb[2] | ((unsigned)hb[3] << 16);
    pk.z = (unsigned)hb[4] | ((unsigned)hb[5] << 16);
    pk.w = (unsigned)hb[6] | ((unsigned)hb[7] << 16);
    *(uint4*)&x1b[(size_t)d * 64 + l32 * 8] = pk;
  }
}

__device__ void agg2_one64(int d, int lane, const int* __restrict__ row_ptr,
                           const int* __restrict__ degarr,
                           const unsigned* __restrict__ sorted, const float* __restrict__ aa,
                           const unsigned short* __restrict__ h2b, const float* __restrict__ b2,
                           float* __restrict__ out){
  int rp0 = row_ptr[d];
  int deg = degarr[d];
  float ad = aa[d * 2 + 1];
  int s = -1;
  if (lane < deg) s = (int)(sorted[rp0 + lane] & 0xffffu);
  else if (lane == deg) s = d;
  float e = -INFINITY;
  if (s >= 0){
    float t = aa[s * 2 + 0] + ad;
    e = t >= 0.f ? t : NEG_SLOPE * t;
  }
  float m = wmax(e);
  float p = (s >= 0) ? __expf(e - m) : 0.f;
  float al = p * __builtin_amdgcn_rcpf(wsum(p) + 1e-16f);
  int ne = deg + 1;
  int g = lane >> 3, c = lane & 7;
  const uint4* hp = (const uint4*)h2b;
  v2f acc[4] = {{0.f,0.f},{0.f,0.f},{0.f,0.f},{0.f,0.f}};
  for (int j0 = 0; j0 < ne; j0 += 32){
    uint4 v[4]; float av[4];
    #pragma unroll
    for (int b = 0; b < 4; b++){
      int j = j0 + b * 8 + g;
      int sj = __shfl(s, j);
      av[b] = __shfl(al, j);
      if (j < ne) v[b] = hp[(size_t)sj * 8 + c];
    }
    #pragma unroll
    for (int b = 0; b < 4; b++){
      if (j0 + b * 8 + g < ne){
        v2f aw = {av[b], av[b]};
        acc[0] = aw * up2(v[b].x) + acc[0];
        acc[1] = aw * up2(v[b].y) + acc[1];
        acc[2] = aw * up2(v[b].z) + acc[2];
        acc[3] = aw * up2(v[b].w) + acc[3];
      }
    }
  }
  float accf[8] = {acc[0][0], acc[0][1], acc[1][0], acc[1][1],
                   acc[2][0], acc[2][1], acc[3][0], acc[3][1]};
  #pragma unroll
  for (int i = 0; i < 8; i++){
    accf[i] += __shfl_xor(accf[i], 8);
    accf[i] += __shfl_xor(accf[i], 16);
    accf[i] += __shfl_xor(accf[i], 32);
  }
  if (lane < 8){
    float r[8];
    #pragma unroll
    for (int i = 0; i < 8; i++) r[i] = accf[i] + b2[lane * 8 + i];
    float* q = &out[(size_t)d * 64 + lane * 8];
    *(float4*)q       = make_float4(r[0], r[1], r[2], r[3]);
    *(float4*)(q + 4) = make_float4(r[4], r[5], r[6], r[7]);
  }
}

__global__ __launch_bounds__(512) void agg_layer2(const int* __restrict__ row_ptr,
    const int* __restrict__ degarr,
    const unsigned* __restrict__ sorted, const float* __restrict__ aa,
    const unsigned short* __restrict__ h2b, const float* __restrict__ b2,
    float* __restrict__ out, int n_nodes, int npair, int nsweep){
  int tid = threadIdx.x;
  int lane = tid & 63;
  if ((int)blockIdx.x >= npair){
    int sw = (blockIdx.x - npair) * 8 + (tid >> 6);
    int chunk = (n_nodes + nsweep - 1) / nsweep;
    int a = sw * chunk;
    int bnd = a + chunk; if (bnd > n_nodes) bnd = n_nodes;
    for (int i0 = a; i0 < bnd; i0 += 64){
      int idx = i0 + lane;
      int dg = 0;
      if (idx < bnd) dg = degarr[idx];
      unsigned long long m = __ballot(dg > 31);
      while (m){
        int bit = __ffsll((long long)m) - 1;
        m &= m - 1;
        agg2_one64(i0 + bit, lane, row_ptr, degarr, sorted, aa, h2b, b2, out);
      }
    }
    return;
  }
  int wid = (blockIdx.x << 3) + (tid >> 6);
  int half = lane >> 5, l32 = lane & 31;
  int d = wid * 2 + half;
  if (wid * 2 >= n_nodes) return;
  bool valid = d < n_nodes;
  int rp0 = 0, deg = -1;
  if (valid){ rp0 = row_ptr[d]; deg = degarr[d]; }
  bool ok = valid && deg <= 31;
  int ne = ok ? deg + 1 : 0;
  int s = -1;
  if (ok){
    if (l32 < deg) s = (int)(sorted[rp0 + l32] & 0xffffu);
    else if (l32 == deg) s = d;
  }
  float ad = valid ? aa[d * 2 + 1] : 0.f;
  float e = -INFINITY;
  if (s >= 0){
    float t = aa[s * 2 + 0] + ad;
    e = t >= 0.f ? t : NEG_SLOPE * t;
  }
  float m = wmax32(e);
  float p = (s >= 0) ? __expf(e - m) : 0.f;   // unnormalized
  int g = l32 >> 3, c = l32 & 7;
  const uint4* hp = (const uint4*)h2b;
  v2f acc[4] = {{0.f,0.f},{0.f,0.f},{0.f,0.f},{0.f,0.f}};
  float dn = 0.f;
  {
    int sj[8]; float pv[8];
    #pragma unroll
    for (int b = 0; b < 8; b++){
      int j = 4 * b + g;
      sj[b] = __shfl(s, j, 32);
      pv[b] = __shfl(p, j, 32);
    }
    uint4 v[8];
    #pragma unroll
    for (int b = 0; b < 8; b++){
      if (4 * b + g < ne) v[b] = hp[(size_t)sj[b] * 8 + c];
    }
    #pragma unroll
    for (int b = 0; b < 8; b++){
      if (4 * b + g < ne){
        v2f aw = {pv[b], pv[b]};
        acc[0] = aw * up2(v[b].x) + acc[0];
        acc[1] = aw * up2(v[b].y) + acc[1];
        acc[2] = aw * up2(v[b].z) + acc[2];
        acc[3] = aw * up2(v[b].w) + acc[3];
        dn += pv[b];
      }
    }
  }
  float accf[8] = {acc[0][0], acc[0][1], acc[1][0], acc[1][1],
                   acc[2][0], acc[2][1], acc[3][0], acc[3][1]};
  #pragma unroll
  for (int i = 0; i < 8; i++){
    accf[i] += __shfl_xor(accf[i], 8, 32);
    accf[i] += __shfl_xor(accf[i], 16, 32);
  }
  dn += __shfl_xor(dn, 8, 32);
  dn += __shfl_xor(dn, 16, 32);
  float inv = __builtin_amdgcn_rcpf(dn);   // dn >= 1 (self-loop) when ok
  if (ok && l32 < 8){
    float r[8];
    #pragma unroll
    for (int i = 0; i < 8; i++) r[i] = accf[i] * inv + b2[l32 * 8 + i];
    float* q = &out[(size_t)d * 64 + l32 * 8];
    *(float4*)q       = make_float4(r[0], r[1], r[2], r[3]);
    *(float4*)(q + 4) = make_float4(r[4], r[5], r[6], r[7]);
  }
}

extern "C" void kernel_launch(void* const* d_in, const int* in_sizes, int n_in,
                              void* d_out, int out_size, void* d_ws, size_t ws_size,
                              hipStream_t stream){
  const float* x     = (const float*)d_in[0];
  const int*   ei    = (const int*)d_in[1];
  const float* W1    = (const float*)d_in[2];
  const float* asrc1 = (const float*)d_in[3];
  const float* adst1 = (const float*)d_in[4];
  const float* b1    = (const float*)d_in[5];
  const float* W2    = (const float*)d_in[6];
  const float* asrc2 = (const float*)d_in[7];
  const float* adst2 = (const float*)d_in[8];
  const float* b2    = (const float*)d_in[9];
  float* out = (float*)d_out;
  int N = in_sizes[0] / IN_DIM;   // 50000 (< 65536 for 16-bit packing)
  int E = in_sizes[1] / 2;
  int NBLK = (E + CHUNK - 1) / CHUNK;       // edge chunks (196)
  int npair = (N + 15) / 16;                // 2 nodes/wave, 8 waves/block
  int GT = (N + 63) / 64;                   // gemm1 blocks (782)

  char* p = (char*)d_ws;
  unsigned short* h1b = (unsigned short*)p;  p += (size_t)N * 128 * 2;
  unsigned short* h2b = (unsigned short*)p;  p += (size_t)N * 64 * 2;
  unsigned short* x1b = (unsigned short*)p;  p += (size_t)N * 64 * 2;
  float* aa1 = (float*)p;                    p += (size_t)N * 4 * 4;
  float* aa2 = (float*)p;                    p += (size_t)N * 2 * 4;
  unsigned* sorted = (unsigned*)p;           p += (size_t)E * 4;
  int* row_ptr   = (int*)p;                  p += (size_t)(N + 1) * 4;
  int* deg       = (int*)p;                  p += (size_t)N * 4;   // zeroed with counter
  int* counter   = (int*)p;                  p += 4;               // adjacent to deg
  int* cur       = (int*)p;                  p += (size_t)N * 4;
  unsigned short* W1t = (unsigned short*)p;  p += 128 * 128 * 2;
  unsigned short* W2t = (unsigned short*)p;

  hipMemsetAsync(deg, 0, ((size_t)N + 1) * sizeof(int), stream);  // deg + counter
  prep<<<NBLK + 80, 256, 0, stream>>>(ei, E, NBLK, deg, W1, W2, W1t, W2t);
  base_assign<<<(N + 1023) / 1024, 1024, 0, stream>>>(deg, row_ptr, cur, counter, N);
  scatter_gemm<<<NBLK + GT, 256, 0, stream>>>(ei, E, cur, sorted, NBLK,
                                              x, W1t, asrc1, adst1, h1b, aa1, N);
  agg_layer1<<<npair + NBIGBLK, 512, 0, stream>>>(row_ptr, deg, sorted, aa1, h1b, b1, x1b,
                                                  N, npair, NBIGBLK * 8);
  gemm2_mfma<<<(N + 127) / 128, 512, 0, stream>>>(x1b, W2t, asrc2, adst2, h2b, aa2, N);
  agg_layer2<<<npair + NBIGBLK, 512, 0, stream>>>(row_ptr, deg, sorted, aa2, h2b, b2, out,
                                                  N, npair, NBIGBLK * 8);
}

// Round 7
// 208.619 us; speedup vs baseline: 1.6447x; 1.1859x over previous
//
#include <hip/hip_runtime.h>
#include <math.h>

#define IN_DIM 128
#define HID 64
#define NEG_SLOPE 0.2f
#define CHUNK 4096
#define GCAP 6144
#define SMEM_UNION 53248
#define NBIGBLK 40

typedef __attribute__((ext_vector_type(8))) short bf16x8;
typedef __attribute__((ext_vector_type(4))) float f32x4;
typedef __attribute__((ext_vector_type(2))) float v2f;

__device__ __forceinline__ float wmax(float v){
  #pragma unroll
  for (int o = 32; o > 0; o >>= 1) v = fmaxf(v, __shfl_xor(v, o));
  return v;
}
__device__ __forceinline__ float wsum(float v){
  #pragma unroll
  for (int o = 32; o > 0; o >>= 1) v += __shfl_xor(v, o);
  return v;
}
__device__ __forceinline__ float wmax32(float v){
  #pragma unroll
  for (int o = 16; o > 0; o >>= 1) v = fmaxf(v, __shfl_xor(v, o, 32));
  return v;
}
__device__ __forceinline__ unsigned short f2bf(float f){
  union { float f; unsigned u; } v; v.f = f;
  unsigned r = v.u + 0x7fffu + ((v.u >> 16) & 1u);
  return (unsigned short)(r >> 16);
}
__device__ __forceinline__ float bl(unsigned u){
  union { unsigned u; float f; } v; v.u = u << 16; return v.f;
}
__device__ __forceinline__ float bh(unsigned u){
  union { unsigned u; float f; } v; v.u = u & 0xffff0000u; return v.f;
}
__device__ __forceinline__ v2f up2(unsigned u){
  v2f r; r[0] = bl(u); r[1] = bh(u); return r;
}

// in-place inclusive scan of sh[0..255], 256 threads (4 waves).
// R6 fix: wave shfl_up scan + 4-entry combine = 2 barriers (was 16).
__device__ __forceinline__ void incl_scan256(int* sh, int tid){
  __shared__ int wt[4];
  int lane = tid & 63, w = tid >> 6;
  int sc = sh[tid];              // own slot only; caller barriers protect
  #pragma unroll
  for (int o = 1; o < 64; o <<= 1){
    int t = __shfl_up(sc, o);
    if (lane >= o) sc += t;
  }
  if (lane == 63) wt[w] = sc;
  __syncthreads();
  int add = 0;
  if (w > 0) add += wt[0];
  if (w > 1) add += wt[1];
  if (w > 2) add += wt[2];
  sh[tid] = sc + add;
  __syncthreads();
}

// ---------- CSR build: 2-phase radix (hi8 scatter -> per-node group) ----------
// R6 lesson: direct counting-sort scatter writes 850k random 4B stores ->
// 64B-line write-amplification (67MB measured vs 17MB ideal) + atomic stalls.
// Radix's LDS staging + contiguous streaming is load-bearing. Reverted.

__device__ void scatter_body(char* smem, const unsigned* __restrict__ packed, int E,
                             const int* __restrict__ binCnt, int* __restrict__ binOff,
                             unsigned* __restrict__ binned, int bx){
  int* ib = (int*)smem;
  int* bc = ib;           // 256
  int* lh = ib + 256;
  int* lbase = ib + 512;
  int* gpos = ib + 768;
  int* lcur = ib + 1024;
  unsigned* buf = (unsigned*)(ib + 1280);   // CHUNK
  int tid = threadIdx.x;
  int cg = binCnt[tid];
  bc[tid] = cg;
  lh[tid] = 0;
  __syncthreads();
  incl_scan256(bc, tid);
  int binBase_t = bc[tid] - cg;
  int base = bx * CHUNK;
  int rem = E - base;
  unsigned v[CHUNK / 256];
  #pragma unroll
  for (int j = 0; j < CHUNK / 256; j++){
    int i = j * 256 + tid;
    if (i < rem){ v[j] = packed[base + i]; atomicAdd(&lh[v[j] >> 24], 1); }
  }
  __syncthreads();
  lbase[tid] = lh[tid]; __syncthreads();
  incl_scan256(lbase, tid);
  int myExcl = tid ? lbase[tid - 1] : 0;
  __syncthreads();
  lbase[tid] = myExcl;
  lcur[tid] = myExcl;
  if (lh[tid] > 0) gpos[tid] = binBase_t + atomicAdd(&binOff[tid], lh[tid]);
  __syncthreads();
  #pragma unroll
  for (int j = 0; j < CHUNK / 256; j++){
    int i = j * 256 + tid;
    if (i < rem){
      int b = v[j] >> 24;
      int p = atomicAdd(&lcur[b], 1);
      buf[p] = v[j];
    }
  }
  __syncthreads();
  int cn = rem < CHUNK ? rem : CHUNK;
  for (int i = tid; i < cn; i += 256){
    unsigned u = buf[i];
    int b = u >> 24;
    binned[gpos[b] + (i - lbase[b])] = u;
  }
}

__device__ void group_body(char* smem, const unsigned* __restrict__ binned,
                           const int* __restrict__ binCnt, unsigned* __restrict__ sorted,
                           int* __restrict__ row_ptr, int N, int g){
  unsigned* A = (unsigned*)smem;            // GCAP
  unsigned* B = A + GCAP;                   // GCAP
  int* ib = (int*)(B + GCAP);
  int* sc = ib;        // 256
  int* h2 = ib + 256;
  int* rs = ib + 512;
  int* cur = ib + 768;
  int tid = threadIdx.x;
  int cg = binCnt[tid];
  sc[tid] = cg;
  h2[tid] = 0;
  __syncthreads();
  incl_scan256(sc, tid);
  int base = sc[g] - binCnt[g];
  int cnt = binCnt[g]; if (cnt > GCAP) cnt = GCAP;
  __syncthreads();
  for (int i = tid; i < cnt; i += 256){
    unsigned u = binned[base + i];
    A[i] = u;
    atomicAdd(&h2[(u >> 16) & 255], 1);
  }
  __syncthreads();
  rs[tid] = h2[tid]; __syncthreads();
  incl_scan256(rs, tid);
  int excl = tid ? rs[tid - 1] : 0;
  __syncthreads();
  rs[tid] = excl; cur[tid] = excl;
  int d = g * 256 + tid;
  if (d < N) row_ptr[d] = base + excl;
  __syncthreads();
  for (int i = tid; i < cnt; i += 256){
    unsigned u = A[i];
    int p = atomicAdd(&cur[(u >> 16) & 255], 1);
    B[p] = u;
  }
  __syncthreads();
  for (int i = tid; i < cnt; i += 256)
    sorted[base + i] = B[i];
}

// ---------- layer-1 GEMM body (MT=64, K=128, NC=128, 2 heads, 256 threads) ----------

__device__ void gemm1_body(char* smem, const float* __restrict__ X,
                           const unsigned short* __restrict__ Wt,
                           const float* __restrict__ asrc, const float* __restrict__ adst,
                           unsigned short* __restrict__ Hb, float* __restrict__ aa,
                           int n_rows, int n0){
  const int KP = 136, CP = 132;
  unsigned short* xa = (unsigned short*)smem;   // [64][136]
  unsigned short* wl = xa + 64 * KP;            // [128][136]
  int tid = threadIdx.x;
  for (int idx = tid; idx < 64 * 32; idx += 256){
    int n = idx >> 5, k4 = idx & 31;
    float4 v = make_float4(0.f, 0.f, 0.f, 0.f);
    if (n0 + n < n_rows) v = *(const float4*)&X[(size_t)(n0 + n) * 128 + k4 * 4];
    ushort4 pk; pk.x = f2bf(v.x); pk.y = f2bf(v.y); pk.z = f2bf(v.z); pk.w = f2bf(v.w);
    *(ushort4*)&xa[n * KP + k4 * 4] = pk;
  }
  for (int idx = tid; idx < 128 * 16; idx += 256){
    int n = idx >> 4, k8 = idx & 15;
    uint4 v = *(const uint4*)&Wt[(size_t)n * 128 + k8 * 8];
    *(uint4*)&wl[n * KP + k8 * 8] = v;
  }
  __syncthreads();

  int lane = tid & 63, w = tid >> 6;
  int m = lane & 15, q = lane >> 4;
  f32x4 acc[4][2];
  #pragma unroll
  for (int i = 0; i < 4; i++)
    #pragma unroll
    for (int j = 0; j < 2; j++)
      #pragma unroll
      for (int r = 0; r < 4; r++) acc[i][j][r] = 0.f;
  #pragma unroll
  for (int ks = 0; ks < 4; ks++){
    bf16x8 bg[2];
    #pragma unroll
    for (int j = 0; j < 2; j++)
      bg[j] = *(const bf16x8*)&wl[((2 * w + j) * 16 + m) * KP + ks * 32 + q * 8];
    #pragma unroll
    for (int i = 0; i < 4; i++){
      bf16x8 af = *(const bf16x8*)&xa[(i * 16 + m) * KP + ks * 32 + q * 8];
      #pragma unroll
      for (int j = 0; j < 2; j++)
        acc[i][j] = __builtin_amdgcn_mfma_f32_16x16x32_bf16(af, bg[j], acc[i][j], 0, 0, 0);
    }
  }
  __syncthreads();
  float* C = (float*)smem;   // [64][132]
  #pragma unroll
  for (int i = 0; i < 4; i++)
    #pragma unroll
    for (int j = 0; j < 2; j++)
      #pragma unroll
      for (int r = 0; r < 4; r++)
        C[(i * 16 + q * 4 + r) * CP + (2 * w + j) * 16 + m] = acc[i][j][r];
  __syncthreads();

  int row = tid >> 2;
  int c0 = (tid & 3) * 32;
  int n = n0 + row;
  int head = (tid & 3) >> 1;
  float s_p = 0.f, d_p = 0.f;
  unsigned short hb[32];
  #pragma unroll
  for (int c = 0; c < 32; c += 4){
    f32x4 v = *(const f32x4*)&C[row * CP + c0 + c];
    #pragma unroll
    for (int u = 0; u < 4; u++){
      int ch = (c0 + c + u) & 63;
      s_p += v[u] * asrc[head * 64 + ch];
      d_p += v[u] * adst[head * 64 + ch];
      hb[c + u] = f2bf(v[u]);
    }
  }
  if (n < n_rows){
    #pragma unroll
    for (int c = 0; c < 32; c += 8){
      uint4 pk;
      pk.x = (unsigned)hb[c]     | ((unsigned)hb[c + 1] << 16);
      pk.y = (unsigned)hb[c + 2] | ((unsigned)hb[c + 3] << 16);
      pk.z = (unsigned)hb[c + 4] | ((unsigned)hb[c + 5] << 16);
      pk.w = (unsigned)hb[c + 6] | ((unsigned)hb[c + 7] << 16);
      *(uint4*)&Hb[(size_t)n * 128 + c0 + c] = pk;
    }
  }
  s_p += __shfl_xor(s_p, 1);
  d_p += __shfl_xor(d_p, 1);
  if ((tid & 1) == 0 && n < n_rows){
    aa[(size_t)n * 4 + head]     = s_p;
    aa[(size_t)n * 4 + 2 + head] = d_p;
  }
}

// ---------- combined launches: sort phases overlapped with gemm1 halves ----------

__global__ __launch_bounds__(256) void sort_gemm_a(const unsigned* __restrict__ packed, int E,
    const int* __restrict__ binCnt, int* __restrict__ binOff, unsigned* __restrict__ binned,
    int NS, const float* __restrict__ X, const unsigned short* __restrict__ W1t,
    const float* __restrict__ asrc1, const float* __restrict__ adst1,
    unsigned short* __restrict__ h1b, float* __restrict__ aa1, int n_rows){
  __shared__ char smem[SMEM_UNION];
  int bx = blockIdx.x;
  if (bx < NS){
    scatter_body(smem, packed, E, binCnt, binOff, binned, bx);
  } else {
    gemm1_body(smem, X, W1t, asrc1, adst1, h1b, aa1, n_rows, (bx - NS) * 64);
  }
}

__global__ __launch_bounds__(256) void sort_gemm_b(const unsigned* __restrict__ binned,
    const int* __restrict__ binCnt, unsigned* __restrict__ sorted, int* __restrict__ row_ptr,
    int N, int NS, int gofs, const float* __restrict__ X, const unsigned short* __restrict__ W1t,
    const float* __restrict__ asrc1, const float* __restrict__ adst1,
    unsigned short* __restrict__ h1b, float* __restrict__ aa1, int n_rows){
  __shared__ char smem[SMEM_UNION];
  int bx = blockIdx.x;
  if (bx < NS){
    group_body(smem, binned, binCnt, sorted, row_ptr, N, bx);
  } else {
    gemm1_body(smem, X, W1t, asrc1, adst1, h1b, aa1, n_rows, (gofs + bx - NS) * 64);
  }
}

// ---------- prep: pack+hist + W conversion + row_ptr seed ----------

__global__ __launch_bounds__(256) void prep(const int* __restrict__ ei, int E, int NBLK,
                                            unsigned* __restrict__ packed,
                                            int* __restrict__ binCnt,
                                            const float* __restrict__ W1,
                                            const float* __restrict__ W2,
                                            unsigned short* __restrict__ W1t,
                                            unsigned short* __restrict__ W2t,
                                            int* __restrict__ row_ptr, int N){
  int tid = threadIdx.x;
  if ((int)blockIdx.x < NBLK){
    __shared__ int lh[256];
    lh[tid] = 0; __syncthreads();
    int base = blockIdx.x * CHUNK;
    if (((E & 3) == 0) && (base + CHUNK <= E)){
      // full chunk: int4 edge loads, uint4 packed stores
      #pragma unroll
      for (int j = 0; j < 4; j++){
        int e0 = base + j * 1024 + tid * 4;
        int4 sv = *(const int4*)&ei[e0];
        int4 dv = *(const int4*)&ei[E + e0];
        uint4 pk;
        pk.x = ((unsigned)dv.x << 16) | (unsigned)sv.x;
        pk.y = ((unsigned)dv.y << 16) | (unsigned)sv.y;
        pk.z = ((unsigned)dv.z << 16) | (unsigned)sv.z;
        pk.w = ((unsigned)dv.w << 16) | (unsigned)sv.w;
        *(uint4*)&packed[e0] = pk;
        atomicAdd(&lh[dv.x >> 8], 1);
        atomicAdd(&lh[dv.y >> 8], 1);
        atomicAdd(&lh[dv.z >> 8], 1);
        atomicAdd(&lh[dv.w >> 8], 1);
      }
    } else {
      #pragma unroll
      for (int j = 0; j < CHUNK / 256; j++){
        int e = base + j * 256 + tid;
        if (e < E){
          unsigned s = (unsigned)ei[e];
          unsigned d = (unsigned)ei[E + e];
          packed[e] = (d << 16) | s;
          atomicAdd(&lh[d >> 8], 1);
        }
      }
    }
    __syncthreads();
    if (lh[tid] > 0) atomicAdd(&binCnt[tid], lh[tid]);
  } else {
    int t = (blockIdx.x - NBLK) * 256 + tid;
    if (t < 128 * 128){
      int n = t >> 7, k = t & 127;
      W1t[n * 128 + k] = f2bf(W1[k * 128 + n]);
    }
    int t2 = t - 128 * 128;
    if (t2 >= 0 && t2 < 64 * 64){
      int n = t2 >> 6, k = t2 & 63;
      W2t[n * 64 + k] = f2bf(W2[k * 64 + n]);
    }
    if (t == 0) row_ptr[N] = E;
  }
}

// ---------- layer-2 GEMM (bf16 input x1b, M-tile 128, 512 threads) ----------

__global__ __launch_bounds__(512) void gemm2_mfma(const unsigned short* __restrict__ Xb,
    const unsigned short* __restrict__ Wt, const float* __restrict__ asrc,
    const float* __restrict__ adst, unsigned short* __restrict__ Hb,
    float* __restrict__ aa, int n_rows)
{
  constexpr int K = 64, NC = 64;
  constexpr int MT = 128;
  constexpr int KP = K + 8;
  constexpr int CP = NC + 4;
  constexpr int MFW = 4;
  constexpr unsigned SM1 = (unsigned)(MT + NC) * KP * 2;
  constexpr unsigned SM2 = (unsigned)MT * CP * 4;
  __shared__ char smem[SM1 > SM2 ? SM1 : SM2];
  unsigned short* xa = (unsigned short*)smem;
  unsigned short* wl = xa + MT * KP;
  int tid = threadIdx.x;
  int n0 = blockIdx.x * MT;

  for (int idx = tid; idx < MT * (K / 8); idx += 512){
    int n = idx >> 3, k8 = idx & 7;
    uint4 v = make_uint4(0u, 0u, 0u, 0u);
    if (n0 + n < n_rows) v = *(const uint4*)&Xb[(size_t)(n0 + n) * K + k8 * 8];
    *(uint4*)&xa[n * KP + k8 * 8] = v;
  }
  for (int idx = tid; idx < NC * (K / 8); idx += 512){
    int n = idx >> 3, k8 = idx & 7;
    uint4 v = *(const uint4*)&Wt[(size_t)n * K + k8 * 8];
    *(uint4*)&wl[n * KP + k8 * 8] = v;
  }
  __syncthreads();

  int lane = tid & 63, w = tid >> 6;
  int m = lane & 15, q = lane >> 4;
  int nf = w & 3;
  int mseg = w >> 2;
  f32x4 acc[MFW];
  #pragma unroll
  for (int i = 0; i < MFW; i++)
    #pragma unroll
    for (int r = 0; r < 4; r++) acc[i][r] = 0.f;

  #pragma unroll
  for (int ks = 0; ks < K / 32; ks++){
    bf16x8 bg = *(const bf16x8*)&wl[(nf * 16 + m) * KP + ks * 32 + q * 8];
    #pragma unroll
    for (int i = 0; i < MFW; i++){
      bf16x8 af = *(const bf16x8*)&xa[((mseg * MFW + i) * 16 + m) * KP + ks * 32 + q * 8];
      acc[i] = __builtin_amdgcn_mfma_f32_16x16x32_bf16(af, bg, acc[i], 0, 0, 0);
    }
  }
  __syncthreads();
  float* C = (float*)smem;
  #pragma unroll
  for (int i = 0; i < MFW; i++)
    #pragma unroll
    for (int r = 0; r < 4; r++)
      C[((mseg * MFW + i) * 16 + q * 4 + r) * CP + nf * 16 + m] = acc[i][r];
  __syncthreads();

  constexpr int CH = NC / 4;   // 16
  int row = tid >> 2;
  int c0 = (tid & 3) * CH;
  int n = n0 + row;
  float s_p = 0.f, d_p = 0.f;
  unsigned short hb[CH];
  #pragma unroll
  for (int c = 0; c < CH; c += 4){
    f32x4 v = *(const f32x4*)&C[row * CP + c0 + c];
    #pragma unroll
    for (int u = 0; u < 4; u++){
      int ch = (c0 + c + u) & 63;
      s_p += v[u] * asrc[ch];
      d_p += v[u] * adst[ch];
      hb[c + u] = f2bf(v[u]);
    }
  }
  if (n < n_rows){
    #pragma unroll
    for (int c = 0; c < CH; c += 8){
      uint4 pk;
      pk.x = (unsigned)hb[c]     | ((unsigned)hb[c + 1] << 16);
      pk.y = (unsigned)hb[c + 2] | ((unsigned)hb[c + 3] << 16);
      pk.z = (unsigned)hb[c + 4] | ((unsigned)hb[c + 5] << 16);
      pk.w = (unsigned)hb[c + 6] | ((unsigned)hb[c + 7] << 16);
      *(uint4*)&Hb[(size_t)n * NC + c0 + c] = pk;
    }
  }
  s_p += __shfl_xor(s_p, 1);
  d_p += __shfl_xor(d_p, 1);
  s_p += __shfl_xor(s_p, 2);
  d_p += __shfl_xor(d_p, 2);
  if ((tid & 3) == 0 && n < n_rows){
    aa[(size_t)n * 2]     = s_p;
    aa[(size_t)n * 2 + 1] = d_p;
  }
}

// ---------- softmax + aggregation (CSR), 2 nodes per wave, deep-MLP gather ----------

__device__ void agg1_one64(int d, int lane, const int* __restrict__ row_ptr,
                           const unsigned* __restrict__ sorted, const float* __restrict__ aa,
                           const unsigned short* __restrict__ h1b, const float* __restrict__ b1,
                           unsigned short* __restrict__ x1b){
  int rp0 = row_ptr[d];
  int deg = row_ptr[d + 1] - rp0;
  float2 adv = *(const float2*)&aa[d * 4 + 2];
  int s = -1;
  if (lane < deg) s = (int)(sorted[rp0 + lane] & 0xffffu);
  else if (lane == deg) s = d;
  float e0 = -INFINITY, e1 = -INFINITY;
  if (s >= 0){
    float2 asv = *(const float2*)&aa[s * 4];
    float t0 = asv.x + adv.x;
    float t1 = asv.y + adv.y;
    e0 = t0 >= 0.f ? t0 : NEG_SLOPE * t0;
    e1 = t1 >= 0.f ? t1 : NEG_SLOPE * t1;
  }
  float m0 = wmax(e0), m1 = wmax(e1);
  float p0 = (s >= 0) ? __expf(e0 - m0) : 0.f;
  float p1 = (s >= 0) ? __expf(e1 - m1) : 0.f;
  float al0 = p0 * __builtin_amdgcn_rcpf(wsum(p0) + 1e-16f);
  float al1 = p1 * __builtin_amdgcn_rcpf(wsum(p1) + 1e-16f);
  int ne = deg + 1;
  int g = lane >> 4, c = lane & 15;
  bool hsel = (c < 8);
  const uint4* hp = (const uint4*)h1b;
  v2f acc[4] = {{0.f,0.f},{0.f,0.f},{0.f,0.f},{0.f,0.f}};
  for (int j0 = 0; j0 < ne; j0 += 16){
    uint4 v[4]; float av[4];
    #pragma unroll
    for (int b = 0; b < 4; b++){
      int j = j0 + b * 4 + g;
      int sj = __shfl(s, j);
      float a0 = __shfl(al0, j);
      float a1 = __shfl(al1, j);
      av[b] = hsel ? a0 : a1;
      if (j < ne) v[b] = hp[(size_t)sj * 16 + c];
    }
    #pragma unroll
    for (int b = 0; b < 4; b++){
      if (j0 + b * 4 + g < ne){
        v2f aw = {av[b], av[b]};
        acc[0] = aw * up2(v[b].x) + acc[0];
        acc[1] = aw * up2(v[b].y) + acc[1];
        acc[2] = aw * up2(v[b].z) + acc[2];
        acc[3] = aw * up2(v[b].w) + acc[3];
      }
    }
  }
  float accf[8] = {acc[0][0], acc[0][1], acc[1][0], acc[1][1],
                   acc[2][0], acc[2][1], acc[3][0], acc[3][1]};
  #pragma unroll
  for (int i = 0; i < 8; i++){
    accf[i] += __shfl_xor(accf[i], 16);
    accf[i] += __shfl_xor(accf[i], 32);
  }
  float outv[8];
  #pragma unroll
  for (int i = 0; i < 8; i++){
    float o = __shfl_xor(accf[i], 8);
    outv[i] = 0.5f * (accf[i] + o);
  }
  if (g == 0 && c < 8){
    unsigned short hb[8];
    #pragma unroll
    for (int i = 0; i < 8; i++){
      float v = outv[i] + b1[c * 8 + i];
      float r = v > 0.f ? v : __expf(v) - 1.0f;
      hb[i] = f2bf(r);
    }
    uint4 pk;
    pk.x = (unsigned)hb[0] | ((unsigned)hb[1] << 16);
    pk.y = (unsigned)hb[2] | ((unsigned)hb[3] << 16);
    pk.z = (unsigned)hb[4] | ((unsigned)hb[5] << 16);
    pk.w = (unsigned)hb[6] | ((unsigned)hb[7] << 16);
    *(uint4*)&x1b[(size_t)d * 64 + c * 8] = pk;
  }
}

__global__ __launch_bounds__(512) void agg_layer1(const int* __restrict__ row_ptr,
    const unsigned* __restrict__ sorted, const float* __restrict__ aa,
    const unsigned short* __restrict__ h1b, const float* __restrict__ b1,
    unsigned short* __restrict__ x1b, int n_nodes, int npair, int nsweep){
  int tid = threadIdx.x;
  int lane = tid & 63;
  if ((int)blockIdx.x >= npair){
    // sweep: find deg>31 nodes, run 64-lane path on each
    int sw = (blockIdx.x - npair) * 8 + (tid >> 6);
    int chunk = (n_nodes + nsweep - 1) / nsweep;
    int a = sw * chunk;
    int bnd = a + chunk; if (bnd > n_nodes) bnd = n_nodes;
    for (int i0 = a; i0 < bnd; i0 += 64){
      int idx = i0 + lane;
      int dg = 0;
      if (idx < bnd) dg = row_ptr[idx + 1] - row_ptr[idx];
      unsigned long long m = __ballot(dg > 31);
      while (m){
        int bit = __ffsll((long long)m) - 1;
        m &= m - 1;
        agg1_one64(i0 + bit, lane, row_ptr, sorted, aa, h1b, b1, x1b);
      }
    }
    return;
  }
  int wid = (blockIdx.x << 3) + (tid >> 6);
  int half = lane >> 5, l32 = lane & 31;
  int d = wid * 2 + half;
  if (wid * 2 >= n_nodes) return;
  bool valid = d < n_nodes;
  int rp0 = 0, deg = -1;
  if (valid){ rp0 = row_ptr[d]; deg = row_ptr[d + 1] - rp0; }
  bool ok = valid && deg <= 31;
  int ne = ok ? deg + 1 : 0;
  int s = -1;
  if (ok){
    if (l32 < deg) s = (int)(sorted[rp0 + l32] & 0xffffu);
    else if (l32 == deg) s = d;
  }
  float2 adv = make_float2(0.f, 0.f);
  if (valid) adv = *(const float2*)&aa[d * 4 + 2];
  float e0 = -INFINITY, e1 = -INFINITY;
  if (s >= 0){
    float2 asv = *(const float2*)&aa[s * 4];
    float t0 = asv.x + adv.x;
    float t1 = asv.y + adv.y;
    e0 = t0 >= 0.f ? t0 : NEG_SLOPE * t0;
    e1 = t1 >= 0.f ? t1 : NEG_SLOPE * t1;
  }
  float m0 = wmax32(e0), m1 = wmax32(e1);
  float p0 = (s >= 0) ? __expf(e0 - m0) : 0.f;   // unnormalized
  float p1 = (s >= 0) ? __expf(e1 - m1) : 0.f;
  int g = l32 >> 4, c = l32 & 15;
  bool hsel = (c < 8);
  const uint4* hp = (const uint4*)h1b;
  v2f acc[4] = {{0.f,0.f},{0.f,0.f},{0.f,0.f},{0.f,0.f}};
  float dn = 0.f;
  // phase 1: j in [0,16)  -- all shuffles first, then 8 gathers in flight
  {
    int sj[8]; float pv[8];
    #pragma unroll
    for (int b = 0; b < 8; b++){
      int j = 2 * b + g;
      sj[b] = __shfl(s, j, 32);
      float q0 = __shfl(p0, j, 32);
      float q1 = __shfl(p1, j, 32);
      pv[b] = hsel ? q0 : q1;
    }
    uint4 v[8];
    #pragma unroll
    for (int b = 0; b < 8; b++){
      if (2 * b + g < ne) v[b] = hp[(size_t)sj[b] * 16 + c];
    }
    #pragma unroll
    for (int b = 0; b < 8; b++){
      if (2 * b + g < ne){
        v2f aw = {pv[b], pv[b]};
        acc[0] = aw * up2(v[b].x) + acc[0];
        acc[1] = aw * up2(v[b].y) + acc[1];
        acc[2] = aw * up2(v[b].z) + acc[2];
        acc[3] = aw * up2(v[b].w) + acc[3];
        dn += pv[b];
      }
    }
  }
  // phase 2: j in [16,32)
  if (ne > 16){
    int sj[8]; float pv[8];
    #pragma unroll
    for (int b = 0; b < 8; b++){
      int j = 16 + 2 * b + g;
      sj[b] = __shfl(s, j, 32);
      float q0 = __shfl(p0, j, 32);
      float q1 = __shfl(p1, j, 32);
      pv[b] = hsel ? q0 : q1;
    }
    uint4 v[8];
    #pragma unroll
    for (int b = 0; b < 8; b++){
      if (16 + 2 * b + g < ne) v[b] = hp[(size_t)sj[b] * 16 + c];
    }
    #pragma unroll
    for (int b = 0; b < 8; b++){
      if (16 + 2 * b + g < ne){
        v2f aw = {pv[b], pv[b]};
        acc[0] = aw * up2(v[b].x) + acc[0];
        acc[1] = aw * up2(v[b].y) + acc[1];
        acc[2] = aw * up2(v[b].z) + acc[2];
        acc[3] = aw * up2(v[b].w) + acc[3];
        dn += pv[b];
      }
    }
  }
  float accf[8] = {acc[0][0], acc[0][1], acc[1][0], acc[1][1],
                   acc[2][0], acc[2][1], acc[3][0], acc[3][1]};
  #pragma unroll
  for (int i = 0; i < 8; i++) accf[i] += __shfl_xor(accf[i], 16, 32);
  dn += __shfl_xor(dn, 16, 32);
  float inv = __builtin_amdgcn_rcpf(dn);   // dn >= 1 (self-loop) when ok
  float outv[8];
  #pragma unroll
  for (int i = 0; i < 8; i++){
    float r = accf[i] * inv;
    float o = __shfl_xor(r, 8, 32);
    outv[i] = 0.5f * (r + o);
  }
  if (ok && l32 < 8){
    unsigned short hb[8];
    #pragma unroll
    for (int i = 0; i < 8; i++){
      float v = outv[i] + b1[l32 * 8 + i];
      float r = v > 0.f ? v : __expf(v) - 1.0f;
      hb[i] = f2bf(r);
    }
    uint4 pk;
    pk.x = (unsigned)hb[0] | ((unsigned)hb[1] << 16);
    pk.y = (unsigned)hb[2] | ((unsigned)hb[3] << 16);
    pk.z = (unsigned)hb[4] | ((unsigned)hb[5] << 16);
    pk.w = (unsigned)hb[6] | ((unsigned)hb[7] << 16);
    *(uint4*)&x1b[(size_t)d * 64 + l32 * 8] = pk;
  }
}

__device__ void agg2_one64(int d, int lane, const int* __restrict__ row_ptr,
                           const unsigned* __restrict__ sorted, const float* __restrict__ aa,
                           const unsigned short* __restrict__ h2b, const float* __restrict__ b2,
                           float* __restrict__ out){
  int rp0 = row_ptr[d];
  int deg = row_ptr[d + 1] - rp0;
  float ad = aa[d * 2 + 1];
  int s = -1;
  if (lane < deg) s = (int)(sorted[rp0 + lane] & 0xffffu);
  else if (lane == deg) s = d;
  float e = -INFINITY;
  if (s >= 0){
    float t = aa[s * 2 + 0] + ad;
    e = t >= 0.f ? t : NEG_SLOPE * t;
  }
  float m = wmax(e);
  float p = (s >= 0) ? __expf(e - m) : 0.f;
  float al = p * __builtin_amdgcn_rcpf(wsum(p) + 1e-16f);
  int ne = deg + 1;
  int g = lane >> 3, c = lane & 7;
  const uint4* hp = (const uint4*)h2b;
  v2f acc[4] = {{0.f,0.f},{0.f,0.f},{0.f,0.f},{0.f,0.f}};
  for (int j0 = 0; j0 < ne; j0 += 32){
    uint4 v[4]; float av[4];
    #pragma unroll
    for (int b = 0; b < 4; b++){
      int j = j0 + b * 8 + g;
      int sj = __shfl(s, j);
      av[b] = __shfl(al, j);
      if (j < ne) v[b] = hp[(size_t)sj * 8 + c];
    }
    #pragma unroll
    for (int b = 0; b < 4; b++){
      if (j0 + b * 8 + g < ne){
        v2f aw = {av[b], av[b]};
        acc[0] = aw * up2(v[b].x) + acc[0];
        acc[1] = aw * up2(v[b].y) + acc[1];
        acc[2] = aw * up2(v[b].z) + acc[2];
        acc[3] = aw * up2(v[b].w) + acc[3];
      }
    }
  }
  float accf[8] = {acc[0][0], acc[0][1], acc[1][0], acc[1][1],
                   acc[2][0], acc[2][1], acc[3][0], acc[3][1]};
  #pragma unroll
  for (int i = 0; i < 8; i++){
    accf[i] += __shfl_xor(accf[i], 8);
    accf[i] += __shfl_xor(accf[i], 16);
    accf[i] += __shfl_xor(accf[i], 32);
  }
  if (lane < 8){
    float r[8];
    #pragma unroll
    for (int i = 0; i < 8; i++) r[i] = accf[i] + b2[lane * 8 + i];
    float* q = &out[(size_t)d * 64 + lane * 8];
    *(float4*)q       = make_float4(r[0], r[1], r[2], r[3]);
    *(float4*)(q + 4) = make_float4(r[4], r[5], r[6], r[7]);
  }
}

__global__ __launch_bounds__(512) void agg_layer2(const int* __restrict__ row_ptr,
    const unsigned* __restrict__ sorted, const float* __restrict__ aa,
    const unsigned short* __restrict__ h2b, const float* __restrict__ b2,
    float* __restrict__ out, int n_nodes, int npair, int nsweep){
  int tid = threadIdx.x;
  int lane = tid & 63;
  if ((int)blockIdx.x >= npair){
    int sw = (blockIdx.x - npair) * 8 + (tid >> 6);
    int chunk = (n_nodes + nsweep - 1) / nsweep;
    int a = sw * chunk;
    int bnd = a + chunk; if (bnd > n_nodes) bnd = n_nodes;
    for (int i0 = a; i0 < bnd; i0 += 64){
      int idx = i0 + lane;
      int dg = 0;
      if (idx < bnd) dg = row_ptr[idx + 1] - row_ptr[idx];
      unsigned long long m = __ballot(dg > 31);
      while (m){
        int bit = __ffsll((long long)m) - 1;
        m &= m - 1;
        agg2_one64(i0 + bit, lane, row_ptr, sorted, aa, h2b, b2, out);
      }
    }
    return;
  }
  int wid = (blockIdx.x << 3) + (tid >> 6);
  int half = lane >> 5, l32 = lane & 31;
  int d = wid * 2 + half;
  if (wid * 2 >= n_nodes) return;
  bool valid = d < n_nodes;
  int rp0 = 0, deg = -1;
  if (valid){ rp0 = row_ptr[d]; deg = row_ptr[d + 1] - rp0; }
  bool ok = valid && deg <= 31;
  int ne = ok ? deg + 1 : 0;
  int s = -1;
  if (ok){
    if (l32 < deg) s = (int)(sorted[rp0 + l32] & 0xffffu);
    else if (l32 == deg) s = d;
  }
  float ad = valid ? aa[d * 2 + 1] : 0.f;
  float e = -INFINITY;
  if (s >= 0){
    float t = aa[s * 2 + 0] + ad;
    e = t >= 0.f ? t : NEG_SLOPE * t;
  }
  float m = wmax32(e);
  float p = (s >= 0) ? __expf(e - m) : 0.f;   // unnormalized
  int g = l32 >> 3, c = l32 & 7;
  const uint4* hp = (const uint4*)h2b;
  v2f acc[4] = {{0.f,0.f},{0.f,0.f},{0.f,0.f},{0.f,0.f}};
  float dn = 0.f;
  // single phase: j = 4*b + g covers j in [0,32) -- 8 gathers in flight
  {
    int sj[8]; float pv[8];
    #pragma unroll
    for (int b = 0; b < 8; b++){
      int j = 4 * b + g;
      sj[b] = __shfl(s, j, 32);
      pv[b] = __shfl(p, j, 32);
    }
    uint4 v[8];
    #pragma unroll
    for (int b = 0; b < 8; b++){
      if (4 * b + g < ne) v[b] = hp[(size_t)sj[b] * 8 + c];
    }
    #pragma unroll
    for (int b = 0; b < 8; b++){
      if (4 * b + g < ne){
        v2f aw = {pv[b], pv[b]};
        acc[0] = aw * up2(v[b].x) + acc[0];
        acc[1] = aw * up2(v[b].y) + acc[1];
        acc[2] = aw * up2(v[b].z) + acc[2];
        acc[3] = aw * up2(v[b].w) + acc[3];
        dn += pv[b];
      }
    }
  }
  float accf[8] = {acc[0][0], acc[0][1], acc[1][0], acc[1][1],
                   acc[2][0], acc[2][1], acc[3][0], acc[3][1]};
  #pragma unroll
  for (int i = 0; i < 8; i++){
    accf[i] += __shfl_xor(accf[i], 8, 32);
    accf[i] += __shfl_xor(accf[i], 16, 32);
  }
  dn += __shfl_xor(dn, 8, 32);
  dn += __shfl_xor(dn, 16, 32);
  float inv = __builtin_amdgcn_rcpf(dn);   // dn >= 1 (self-loop) when ok
  if (ok && l32 < 8){
    float r[8];
    #pragma unroll
    for (int i = 0; i < 8; i++) r[i] = accf[i] * inv + b2[l32 * 8 + i];
    float* q = &out[(size_t)d * 64 + l32 * 8];
    *(float4*)q       = make_float4(r[0], r[1], r[2], r[3]);
    *(float4*)(q + 4) = make_float4(r[4], r[5], r[6], r[7]);
  }
}

extern "C" void kernel_launch(void* const* d_in, const int* in_sizes, int n_in,
                              void* d_out, int out_size, void* d_ws, size_t ws_size,
                              hipStream_t stream){
  const float* x     = (const float*)d_in[0];
  const int*   ei    = (const int*)d_in[1];
  const float* W1    = (const float*)d_in[2];
  const float* asrc1 = (const float*)d_in[3];
  const float* adst1 = (const float*)d_in[4];
  const float* b1    = (const float*)d_in[5];
  const float* W2    = (const float*)d_in[6];
  const float* asrc2 = (const float*)d_in[7];
  const float* adst2 = (const float*)d_in[8];
  const float* b2    = (const float*)d_in[9];
  float* out = (float*)d_out;
  int N = in_sizes[0] / IN_DIM;   // 50000 (< 65536 for 16-bit packing)
  int E = in_sizes[1] / 2;
  int NG = (N + 255) >> 8;                  // coarse bins (196)
  int NBLK = (E + CHUNK - 1) / CHUNK;       // scatter blocks (196)
  int npair = (N + 15) / 16;                // 2 nodes/wave, 8 waves/block
  int GT = (N + 63) / 64;                   // total 64-row gemm1 blocks (782)
  int GA = GT / 2;                          // first half with scatter
  int GB = GT - GA;                         // second half with group_sort

  char* p = (char*)d_ws;
  unsigned short* h1b = (unsigned short*)p;  p += (size_t)N * 128 * 2;
  unsigned short* h2b = (unsigned short*)p;  p += (size_t)N * 64 * 2;
  unsigned short* x1b = (unsigned short*)p;  p += (size_t)N * 64 * 2;
  float* aa1 = (float*)p;                    p += (size_t)N * 4 * 4;
  float* aa2 = (float*)p;                    p += (size_t)N * 2 * 4;
  unsigned* packed = (unsigned*)p;           p += (size_t)E * 4;
  unsigned* binned = (unsigned*)p;           p += (size_t)E * 4;
  unsigned* sorted = (unsigned*)p;           p += (size_t)E * 4;
  int* row_ptr   = (int*)p;                  p += (size_t)(N + 1) * 4;
  int* binCnt    = (int*)p;                  p += 256 * 4;
  int* binOff    = (int*)p;                  p += 256 * 4;
  unsigned short* W1t = (unsigned short*)p;  p += 128 * 128 * 2;
  unsigned short* W2t = (unsigned short*)p;

  hipMemsetAsync(binCnt, 0, 512 * sizeof(int), stream);   // binCnt + binOff
  prep<<<NBLK + 80, 256, 0, stream>>>(ei, E, NBLK, packed, binCnt,
                                      W1, W2, W1t, W2t, row_ptr, N);
  sort_gemm_a<<<NBLK + GA, 256, 0, stream>>>(packed, E, binCnt, binOff, binned,
                                             NBLK, x, W1t, asrc1, adst1, h1b, aa1, N);
  sort_gemm_b<<<NG + GB, 256, 0, stream>>>(binned, binCnt, sorted, row_ptr, N,
                                           NG, GA, x, W1t, asrc1, adst1, h1b, aa1, N);
  agg_layer1<<<npair + NBIGBLK, 512, 0, stream>>>(row_ptr, sorted, aa1, h1b, b1, x1b,
                                                  N, npair, NBIGBLK * 8);
  gemm2_mfma<<<(N + 127) / 128, 512, 0, stream>>>(x1b, W2t, asrc2, adst2, h2b, aa2, N);
  agg_layer2<<<npair + NBIGBLK, 512, 0, stream>>>(row_ptr, sorted, aa2, h2b, b2, out,
                                                  N, npair, NBIGBLK * 8);
}

// Round 8
// 208.262 us; speedup vs baseline: 1.6475x; 1.0017x over previous
//
#include <hip/hip_runtime.h>
#include <math.h>

#define IN_DIM 128
#define HID 64
#define NEG_SLOPE 0.2f
#define CHUNK 4096
#define GCAP 6144
#define SMEM_UNION 53248
#define NBIGBLK 40

typedef __attribute__((ext_vector_type(8))) short bf16x8;
typedef __attribute__((ext_vector_type(4))) float f32x4;
typedef __attribute__((ext_vector_type(2))) float v2f;

__device__ __forceinline__ float wmax(float v){
  #pragma unroll
  for (int o = 32; o > 0; o >>= 1) v = fmaxf(v, __shfl_xor(v, o));
  return v;
}
__device__ __forceinline__ float wsum(float v){
  #pragma unroll
  for (int o = 32; o > 0; o >>= 1) v += __shfl_xor(v, o);
  return v;
}
__device__ __forceinline__ float wmax32(float v){
  #pragma unroll
  for (int o = 16; o > 0; o >>= 1) v = fmaxf(v, __shfl_xor(v, o, 32));
  return v;
}
__device__ __forceinline__ unsigned short f2bf(float f){
  union { float f; unsigned u; } v; v.f = f;
  unsigned r = v.u + 0x7fffu + ((v.u >> 16) & 1u);
  return (unsigned short)(r >> 16);
}
__device__ __forceinline__ float bl(unsigned u){
  union { unsigned u; float f; } v; v.u = u << 16; return v.f;
}
__device__ __forceinline__ float bh(unsigned u){
  union { unsigned u; float f; } v; v.u = u & 0xffff0000u; return v.f;
}
__device__ __forceinline__ v2f up2(unsigned u){
  v2f r; r[0] = bl(u); r[1] = bh(u); return r;
}

// in-place inclusive scan of sh[0..255], 256 threads (4 waves).
// R6: wave shfl_up scan + 4-entry combine = 2 barriers (was 16).
__device__ __forceinline__ void incl_scan256(int* sh, int tid){
  __shared__ int wt[4];
  int lane = tid & 63, w = tid >> 6;
  int sc = sh[tid];
  #pragma unroll
  for (int o = 1; o < 64; o <<= 1){
    int t = __shfl_up(sc, o);
    if (lane >= o) sc += t;
  }
  if (lane == 63) wt[w] = sc;
  __syncthreads();
  int add = 0;
  if (w > 0) add += wt[0];
  if (w > 1) add += wt[1];
  if (w > 2) add += wt[2];
  sh[tid] = sc + add;
  __syncthreads();
}

// ---------- CSR build: 2-phase radix (hi8 scatter -> per-node group) ----------
// R8: packed buffer deleted -- scatter reads ei directly (int4) and packs inline.

__device__ void scatter_body(char* smem, const int* __restrict__ ei, int E,
                             const int* __restrict__ binCnt, int* __restrict__ binOff,
                             unsigned* __restrict__ binned, int bx){
  int* ib = (int*)smem;
  int* bc = ib;           // 256
  int* lh = ib + 256;
  int* lbase = ib + 512;
  int* gpos = ib + 768;
  int* lcur = ib + 1024;
  unsigned* buf = (unsigned*)(ib + 1280);   // CHUNK
  int tid = threadIdx.x;
  int cg = binCnt[tid];
  bc[tid] = cg;
  lh[tid] = 0;
  __syncthreads();
  incl_scan256(bc, tid);
  int binBase_t = bc[tid] - cg;
  int base = bx * CHUNK;
  int rem = E - base;
  unsigned v[CHUNK / 256];
  if (((E & 3) == 0) && (base + CHUNK <= E)){
    #pragma unroll
    for (int j = 0; j < 4; j++){
      int e0 = base + j * 1024 + tid * 4;
      int4 sv = *(const int4*)&ei[e0];
      int4 dv = *(const int4*)&ei[E + e0];
      v[j * 4 + 0] = ((unsigned)dv.x << 16) | (unsigned)sv.x;
      v[j * 4 + 1] = ((unsigned)dv.y << 16) | (unsigned)sv.y;
      v[j * 4 + 2] = ((unsigned)dv.z << 16) | (unsigned)sv.z;
      v[j * 4 + 3] = ((unsigned)dv.w << 16) | (unsigned)sv.w;
      atomicAdd(&lh[dv.x >> 8], 1);
      atomicAdd(&lh[dv.y >> 8], 1);
      atomicAdd(&lh[dv.z >> 8], 1);
      atomicAdd(&lh[dv.w >> 8], 1);
    }
    __syncthreads();
    lbase[tid] = lh[tid]; __syncthreads();
    incl_scan256(lbase, tid);
    int myExcl = tid ? lbase[tid - 1] : 0;
    __syncthreads();
    lbase[tid] = myExcl;
    lcur[tid] = myExcl;
    if (lh[tid] > 0) gpos[tid] = binBase_t + atomicAdd(&binOff[tid], lh[tid]);
    __syncthreads();
    #pragma unroll
    for (int j = 0; j < CHUNK / 256; j++){
      int b = v[j] >> 24;
      int p = atomicAdd(&lcur[b], 1);
      buf[p] = v[j];
    }
  } else {
    #pragma unroll
    for (int j = 0; j < CHUNK / 256; j++){
      int i = j * 256 + tid;
      if (i < rem){
        unsigned s = (unsigned)ei[base + i];
        unsigned d = (unsigned)ei[E + base + i];
        v[j] = (d << 16) | s;
        atomicAdd(&lh[v[j] >> 24], 1);
      }
    }
    __syncthreads();
    lbase[tid] = lh[tid]; __syncthreads();
    incl_scan256(lbase, tid);
    int myExcl = tid ? lbase[tid - 1] : 0;
    __syncthreads();
    lbase[tid] = myExcl;
    lcur[tid] = myExcl;
    if (lh[tid] > 0) gpos[tid] = binBase_t + atomicAdd(&binOff[tid], lh[tid]);
    __syncthreads();
    #pragma unroll
    for (int j = 0; j < CHUNK / 256; j++){
      int i = j * 256 + tid;
      if (i < rem){
        int b = v[j] >> 24;
        int p = atomicAdd(&lcur[b], 1);
        buf[p] = v[j];
      }
    }
  }
  __syncthreads();
  int cn = rem < CHUNK ? rem : CHUNK;
  for (int i = tid; i < cn; i += 256){
    unsigned u = buf[i];
    int b = u >> 24;
    binned[gpos[b] + (i - lbase[b])] = u;
  }
}

__device__ void group_body(char* smem, const unsigned* __restrict__ binned,
                           const int* __restrict__ binCnt, unsigned* __restrict__ sorted,
                           int* __restrict__ row_ptr, int N, int g){
  unsigned* A = (unsigned*)smem;            // GCAP
  unsigned* B = A + GCAP;                   // GCAP
  int* ib = (int*)(B + GCAP);
  int* sc = ib;        // 256
  int* h2 = ib + 256;
  int* rs = ib + 512;
  int* cur = ib + 768;
  int tid = threadIdx.x;
  int cg = binCnt[tid];
  sc[tid] = cg;
  h2[tid] = 0;
  __syncthreads();
  incl_scan256(sc, tid);
  int base = sc[g] - binCnt[g];
  int cnt = binCnt[g]; if (cnt > GCAP) cnt = GCAP;
  __syncthreads();
  for (int i = tid; i < cnt; i += 256){
    unsigned u = binned[base + i];
    A[i] = u;
    atomicAdd(&h2[(u >> 16) & 255], 1);
  }
  __syncthreads();
  rs[tid] = h2[tid]; __syncthreads();
  incl_scan256(rs, tid);
  int excl = tid ? rs[tid - 1] : 0;
  __syncthreads();
  rs[tid] = excl; cur[tid] = excl;
  int d = g * 256 + tid;
  if (d < N) row_ptr[d] = base + excl;
  __syncthreads();
  for (int i = tid; i < cnt; i += 256){
    unsigned u = A[i];
    int p = atomicAdd(&cur[(u >> 16) & 255], 1);
    B[p] = u;
  }
  __syncthreads();
  for (int i = tid; i < cnt; i += 256)
    sorted[base + i] = B[i];
}

// ---------- layer-1 GEMM body (MT=64, K=128, NC=128, 2 heads, 256 threads) ----------

__device__ void gemm1_body(char* smem, const float* __restrict__ X,
                           const unsigned short* __restrict__ Wt,
                           const float* __restrict__ asrc, const float* __restrict__ adst,
                           unsigned short* __restrict__ Hb, float* __restrict__ aa,
                           int n_rows, int n0){
  const int KP = 136, CP = 132;
  unsigned short* xa = (unsigned short*)smem;   // [64][136]
  unsigned short* wl = xa + 64 * KP;            // [128][136]
  int tid = threadIdx.x;
  for (int idx = tid; idx < 64 * 32; idx += 256){
    int n = idx >> 5, k4 = idx & 31;
    float4 v = make_float4(0.f, 0.f, 0.f, 0.f);
    if (n0 + n < n_rows) v = *(const float4*)&X[(size_t)(n0 + n) * 128 + k4 * 4];
    ushort4 pk; pk.x = f2bf(v.x); pk.y = f2bf(v.y); pk.z = f2bf(v.z); pk.w = f2bf(v.w);
    *(ushort4*)&xa[n * KP + k4 * 4] = pk;
  }
  for (int idx = tid; idx < 128 * 16; idx += 256){
    int n = idx >> 4, k8 = idx & 15;
    uint4 v = *(const uint4*)&Wt[(size_t)n * 128 + k8 * 8];
    *(uint4*)&wl[n * KP + k8 * 8] = v;
  }
  __syncthreads();

  int lane = tid & 63, w = tid >> 6;
  int m = lane & 15, q = lane >> 4;
  f32x4 acc[4][2];
  #pragma unroll
  for (int i = 0; i < 4; i++)
    #pragma unroll
    for (int j = 0; j < 2; j++)
      #pragma unroll
      for (int r = 0; r < 4; r++) acc[i][j][r] = 0.f;
  #pragma unroll
  for (int ks = 0; ks < 4; ks++){
    bf16x8 bg[2];
    #pragma unroll
    for (int j = 0; j < 2; j++)
      bg[j] = *(const bf16x8*)&wl[((2 * w + j) * 16 + m) * KP + ks * 32 + q * 8];
    #pragma unroll
    for (int i = 0; i < 4; i++){
      bf16x8 af = *(const bf16x8*)&xa[(i * 16 + m) * KP + ks * 32 + q * 8];
      #pragma unroll
      for (int j = 0; j < 2; j++)
        acc[i][j] = __builtin_amdgcn_mfma_f32_16x16x32_bf16(af, bg[j], acc[i][j], 0, 0, 0);
    }
  }
  __syncthreads();
  float* C = (float*)smem;   // [64][132]
  #pragma unroll
  for (int i = 0; i < 4; i++)
    #pragma unroll
    for (int j = 0; j < 2; j++)
      #pragma unroll
      for (int r = 0; r < 4; r++)
        C[(i * 16 + q * 4 + r) * CP + (2 * w + j) * 16 + m] = acc[i][j][r];
  __syncthreads();

  int row = tid >> 2;
  int c0 = (tid & 3) * 32;
  int n = n0 + row;
  int head = (tid & 3) >> 1;
  float s_p = 0.f, d_p = 0.f;
  unsigned short hb[32];
  #pragma unroll
  for (int c = 0; c < 32; c += 4){
    f32x4 v = *(const f32x4*)&C[row * CP + c0 + c];
    #pragma unroll
    for (int u = 0; u < 4; u++){
      int ch = (c0 + c + u) & 63;
      s_p += v[u] * asrc[head * 64 + ch];
      d_p += v[u] * adst[head * 64 + ch];
      hb[c + u] = f2bf(v[u]);
    }
  }
  if (n < n_rows){
    #pragma unroll
    for (int c = 0; c < 32; c += 8){
      uint4 pk;
      pk.x = (unsigned)hb[c]     | ((unsigned)hb[c + 1] << 16);
      pk.y = (unsigned)hb[c + 2] | ((unsigned)hb[c + 3] << 16);
      pk.z = (unsigned)hb[c + 4] | ((unsigned)hb[c + 5] << 16);
      pk.w = (unsigned)hb[c + 6] | ((unsigned)hb[c + 7] << 16);
      *(uint4*)&Hb[(size_t)n * 128 + c0 + c] = pk;
    }
  }
  s_p += __shfl_xor(s_p, 1);
  d_p += __shfl_xor(d_p, 1);
  if ((tid & 1) == 0 && n < n_rows){
    aa[(size_t)n * 4 + head]     = s_p;
    aa[(size_t)n * 4 + 2 + head] = d_p;
  }
}

// ---------- combined launches: sort phases overlapped with gemm1 halves ----------

__global__ __launch_bounds__(256) void sort_gemm_a(const int* __restrict__ ei, int E,
    const int* __restrict__ binCnt, int* __restrict__ binOff, unsigned* __restrict__ binned,
    int NS, const float* __restrict__ X, const unsigned short* __restrict__ W1t,
    const float* __restrict__ asrc1, const float* __restrict__ adst1,
    unsigned short* __restrict__ h1b, float* __restrict__ aa1, int n_rows){
  __shared__ char smem[SMEM_UNION];
  int bx = blockIdx.x;
  if (bx < NS){
    scatter_body(smem, ei, E, binCnt, binOff, binned, bx);
  } else {
    gemm1_body(smem, X, W1t, asrc1, adst1, h1b, aa1, n_rows, (bx - NS) * 64);
  }
}

__global__ __launch_bounds__(256) void sort_gemm_b(const unsigned* __restrict__ binned,
    const int* __restrict__ binCnt, unsigned* __restrict__ sorted, int* __restrict__ row_ptr,
    int N, int NS, int gofs, const float* __restrict__ X, const unsigned short* __restrict__ W1t,
    const float* __restrict__ asrc1, const float* __restrict__ adst1,
    unsigned short* __restrict__ h1b, float* __restrict__ aa1, int n_rows){
  __shared__ char smem[SMEM_UNION];
  int bx = blockIdx.x;
  if (bx < NS){
    group_body(smem, binned, binCnt, sorted, row_ptr, N, bx);
  } else {
    gemm1_body(smem, X, W1t, asrc1, adst1, h1b, aa1, n_rows, (gofs + bx - NS) * 64);
  }
}

// ---------- prep: dst histogram + W conversions + w2a/w2b + row_ptr seed ----------
// R8: gemm2 deleted via linearity -- layer-2 attention logits come from
// w2a = W2 . asrc2, w2b = W2 . adst2 (64-vecs), so aa2 = x1 . w2a computed in
// agg_layer1's epilogue. Final out = agg(x1) @ W2 + b2 in gemm_out.

__global__ __launch_bounds__(256) void prep(const int* __restrict__ ei, int E, int NBLK,
                                            int* __restrict__ binCnt,
                                            const float* __restrict__ W1,
                                            const float* __restrict__ W2,
                                            const float* __restrict__ asrc2,
                                            const float* __restrict__ adst2,
                                            unsigned short* __restrict__ W1t,
                                            unsigned short* __restrict__ W2t,
                                            float* __restrict__ w2a,
                                            float* __restrict__ w2b,
                                            int* __restrict__ row_ptr, int N){
  int tid = threadIdx.x;
  if ((int)blockIdx.x < NBLK){
    __shared__ int lh[256];
    lh[tid] = 0; __syncthreads();
    int base = blockIdx.x * CHUNK;
    if (((E & 3) == 0) && (base + CHUNK <= E)){
      #pragma unroll
      for (int j = 0; j < 4; j++){
        int e0 = base + j * 1024 + tid * 4;
        int4 dv = *(const int4*)&ei[E + e0];
        atomicAdd(&lh[dv.x >> 8], 1);
        atomicAdd(&lh[dv.y >> 8], 1);
        atomicAdd(&lh[dv.z >> 8], 1);
        atomicAdd(&lh[dv.w >> 8], 1);
      }
    } else {
      #pragma unroll
      for (int j = 0; j < CHUNK / 256; j++){
        int e = base + j * 256 + tid;
        if (e < E) atomicAdd(&lh[ei[E + e] >> 8], 1);
      }
    }
    __syncthreads();
    if (lh[tid] > 0) atomicAdd(&binCnt[tid], lh[tid]);
  } else {
    int t = (blockIdx.x - NBLK) * 256 + tid;
    if (t < 128 * 128){
      int n = t >> 7, k = t & 127;
      W1t[n * 128 + k] = f2bf(W1[k * 128 + n]);
    }
    int t2 = t - 128 * 128;
    if (t2 >= 0 && t2 < 64 * 64){
      int n = t2 >> 6, k = t2 & 63;
      W2t[n * 64 + k] = f2bf(W2[k * 64 + n]);
    }
    int t3 = t - (128 * 128 + 64 * 64);
    if (t3 >= 0 && t3 < 64){
      float sa = 0.f, sb = 0.f;
      #pragma unroll
      for (int n = 0; n < 64; n++){
        float wv = W2[t3 * 64 + n];
        sa += wv * asrc2[n];
        sb += wv * adst2[n];
      }
      w2a[t3] = sa;
      w2b[t3] = sb;
    }
    if (t == 0) row_ptr[N] = E;
  }
}

// ---------- final GEMM: out = y1 @ W2 + b2 (M-tile 128, 512 threads) ----------

__global__ __launch_bounds__(512) void gemm_out(const unsigned short* __restrict__ Xb,
    const unsigned short* __restrict__ Wt, const float* __restrict__ b2,
    float* __restrict__ out, int n_rows)
{
  constexpr int K = 64, NC = 64;
  constexpr int MT = 128;
  constexpr int KP = K + 8;
  constexpr int CP = NC + 4;
  constexpr int MFW = 4;
  constexpr unsigned SM1 = (unsigned)(MT + NC) * KP * 2;
  constexpr unsigned SM2 = (unsigned)MT * CP * 4;
  __shared__ char smem[SM1 > SM2 ? SM1 : SM2];
  unsigned short* xa = (unsigned short*)smem;
  unsigned short* wl = xa + MT * KP;
  int tid = threadIdx.x;
  int n0 = blockIdx.x * MT;

  for (int idx = tid; idx < MT * (K / 8); idx += 512){
    int n = idx >> 3, k8 = idx & 7;
    uint4 v = make_uint4(0u, 0u, 0u, 0u);
    if (n0 + n < n_rows) v = *(const uint4*)&Xb[(size_t)(n0 + n) * K + k8 * 8];
    *(uint4*)&xa[n * KP + k8 * 8] = v;
  }
  for (int idx = tid; idx < NC * (K / 8); idx += 512){
    int n = idx >> 3, k8 = idx & 7;
    uint4 v = *(const uint4*)&Wt[(size_t)n * K + k8 * 8];
    *(uint4*)&wl[n * KP + k8 * 8] = v;
  }
  __syncthreads();

  int lane = tid & 63, w = tid >> 6;
  int m = lane & 15, q = lane >> 4;
  int nf = w & 3;
  int mseg = w >> 2;
  f32x4 acc[MFW];
  #pragma unroll
  for (int i = 0; i < MFW; i++)
    #pragma unroll
    for (int r = 0; r < 4; r++) acc[i][r] = 0.f;

  #pragma unroll
  for (int ks = 0; ks < K / 32; ks++){
    bf16x8 bg = *(const bf16x8*)&wl[(nf * 16 + m) * KP + ks * 32 + q * 8];
    #pragma unroll
    for (int i = 0; i < MFW; i++){
      bf16x8 af = *(const bf16x8*)&xa[((mseg * MFW + i) * 16 + m) * KP + ks * 32 + q * 8];
      acc[i] = __builtin_amdgcn_mfma_f32_16x16x32_bf16(af, bg, acc[i], 0, 0, 0);
    }
  }
  __syncthreads();
  float* C = (float*)smem;
  #pragma unroll
  for (int i = 0; i < MFW; i++)
    #pragma unroll
    for (int r = 0; r < 4; r++)
      C[((mseg * MFW + i) * 16 + q * 4 + r) * CP + nf * 16 + m] = acc[i][r];
  __syncthreads();

  int row = tid >> 2;
  int c0 = (tid & 3) * 16;
  int n = n0 + row;
  if (n < n_rows){
    #pragma unroll
    for (int c = 0; c < 16; c += 4){
      f32x4 v = *(const f32x4*)&C[row * CP + c0 + c];
      float4 o;
      o.x = v[0] + b2[c0 + c];
      o.y = v[1] + b2[c0 + c + 1];
      o.z = v[2] + b2[c0 + c + 2];
      o.w = v[3] + b2[c0 + c + 3];
      *(float4*)&out[(size_t)n * 64 + c0 + c] = o;
    }
  }
}

// ---------- softmax + aggregation (CSR), 2 nodes per wave, deep-MLP gather ----------

__device__ void agg1_one64(int d, int lane, const int* __restrict__ row_ptr,
                           const unsigned* __restrict__ sorted, const float* __restrict__ aa,
                           const unsigned short* __restrict__ h1b, const float* __restrict__ b1,
                           const float* __restrict__ w2a, const float* __restrict__ w2b,
                           unsigned short* __restrict__ x1b, float* __restrict__ aa2){
  int rp0 = row_ptr[d];
  int deg = row_ptr[d + 1] - rp0;
  float2 adv = *(const float2*)&aa[d * 4 + 2];
  int s = -1;
  if (lane < deg) s = (int)(sorted[rp0 + lane] & 0xffffu);
  else if (lane == deg) s = d;
  float e0 = -INFINITY, e1 = -INFINITY;
  if (s >= 0){
    float2 asv = *(const float2*)&aa[s * 4];
    float t0 = asv.x + adv.x;
    float t1 = asv.y + adv.y;
    e0 = t0 >= 0.f ? t0 : NEG_SLOPE * t0;
    e1 = t1 >= 0.f ? t1 : NEG_SLOPE * t1;
  }
  float m0 = wmax(e0), m1 = wmax(e1);
  float p0 = (s >= 0) ? __expf(e0 - m0) : 0.f;
  float p1 = (s >= 0) ? __expf(e1 - m1) : 0.f;
  float al0 = p0 * __builtin_amdgcn_rcpf(wsum(p0) + 1e-16f);
  float al1 = p1 * __builtin_amdgcn_rcpf(wsum(p1) + 1e-16f);
  int ne = deg + 1;
  int g = lane >> 4, c = lane & 15;
  bool hsel = (c < 8);
  const uint4* hp = (const uint4*)h1b;
  v2f acc[4] = {{0.f,0.f},{0.f,0.f},{0.f,0.f},{0.f,0.f}};
  for (int j0 = 0; j0 < ne; j0 += 16){
    uint4 v[4]; float av[4];
    #pragma unroll
    for (int b = 0; b < 4; b++){
      int j = j0 + b * 4 + g;
      int sj = __shfl(s, j);
      float a0 = __shfl(al0, j);
      float a1 = __shfl(al1, j);
      av[b] = hsel ? a0 : a1;
      if (j < ne) v[b] = hp[(size_t)sj * 16 + c];
    }
    #pragma unroll
    for (int b = 0; b < 4; b++){
      if (j0 + b * 4 + g < ne){
        v2f aw = {av[b], av[b]};
        acc[0] = aw * up2(v[b].x) + acc[0];
        acc[1] = aw * up2(v[b].y) + acc[1];
        acc[2] = aw * up2(v[b].z) + acc[2];
        acc[3] = aw * up2(v[b].w) + acc[3];
      }
    }
  }
  float accf[8] = {acc[0][0], acc[0][1], acc[1][0], acc[1][1],
                   acc[2][0], acc[2][1], acc[3][0], acc[3][1]};
  #pragma unroll
  for (int i = 0; i < 8; i++){
    accf[i] += __shfl_xor(accf[i], 16);
    accf[i] += __shfl_xor(accf[i], 32);
  }
  float outv[8];
  #pragma unroll
  for (int i = 0; i < 8; i++){
    float o = __shfl_xor(accf[i], 8);
    outv[i] = 0.5f * (accf[i] + o);
  }
  if (g == 0 && c < 8){
    unsigned short hb[8];
    float rr[8];
    #pragma unroll
    for (int i = 0; i < 8; i++){
      float v = outv[i] + b1[c * 8 + i];
      rr[i] = v > 0.f ? v : __expf(v) - 1.0f;
      hb[i] = f2bf(rr[i]);
    }
    uint4 pk;
    pk.x = (unsigned)hb[0] | ((unsigned)hb[1] << 16);
    pk.y = (unsigned)hb[2] | ((unsigned)hb[3] << 16);
    pk.z = (unsigned)hb[4] | ((unsigned)hb[5] << 16);
    pk.w = (unsigned)hb[6] | ((unsigned)hb[7] << 16);
    *(uint4*)&x1b[(size_t)d * 64 + c * 8] = pk;
    float sd = 0.f, dd = 0.f;
    #pragma unroll
    for (int i = 0; i < 8; i++){
      sd += rr[i] * w2a[c * 8 + i];
      dd += rr[i] * w2b[c * 8 + i];
    }
    sd += __shfl_xor(sd, 1); dd += __shfl_xor(dd, 1);
    sd += __shfl_xor(sd, 2); dd += __shfl_xor(dd, 2);
    sd += __shfl_xor(sd, 4); dd += __shfl_xor(dd, 4);
    if (c == 0){
      aa2[(size_t)d * 2]     = sd;
      aa2[(size_t)d * 2 + 1] = dd;
    }
  }
}

__global__ __launch_bounds__(512) void agg_layer1(const int* __restrict__ row_ptr,
    const unsigned* __restrict__ sorted, const float* __restrict__ aa,
    const unsigned short* __restrict__ h1b, const float* __restrict__ b1,
    const float* __restrict__ w2a, const float* __restrict__ w2b,
    unsigned short* __restrict__ x1b, float* __restrict__ aa2,
    int n_nodes, int npair, int nsweep){
  int tid = threadIdx.x;
  int lane = tid & 63;
  if ((int)blockIdx.x >= npair){
    // sweep: find deg>31 nodes, run 64-lane path on each
    int sw = (blockIdx.x - npair) * 8 + (tid >> 6);
    int chunk = (n_nodes + nsweep - 1) / nsweep;
    int a = sw * chunk;
    int bnd = a + chunk; if (bnd > n_nodes) bnd = n_nodes;
    for (int i0 = a; i0 < bnd; i0 += 64){
      int idx = i0 + lane;
      int dg = 0;
      if (idx < bnd) dg = row_ptr[idx + 1] - row_ptr[idx];
      unsigned long long m = __ballot(dg > 31);
      while (m){
        int bit = __ffsll((long long)m) - 1;
        m &= m - 1;
        agg1_one64(i0 + bit, lane, row_ptr, sorted, aa, h1b, b1, w2a, w2b, x1b, aa2);
      }
    }
    return;
  }
  int wid = (blockIdx.x << 3) + (tid >> 6);
  int half = lane >> 5, l32 = lane & 31;
  int d = wid * 2 + half;
  if (wid * 2 >= n_nodes) return;
  bool valid = d < n_nodes;
  int rp0 = 0, deg = -1;
  if (valid){ rp0 = row_ptr[d]; deg = row_ptr[d + 1] - rp0; }
  bool ok = valid && deg <= 31;
  int ne = ok ? deg + 1 : 0;
  int s = -1;
  if (ok){
    if (l32 < deg) s = (int)(sorted[rp0 + l32] & 0xffffu);
    else if (l32 == deg) s = d;
  }
  float2 adv = make_float2(0.f, 0.f);
  if (valid) adv = *(const float2*)&aa[d * 4 + 2];
  float e0 = -INFINITY, e1 = -INFINITY;
  if (s >= 0){
    float2 asv = *(const float2*)&aa[s * 4];
    float t0 = asv.x + adv.x;
    float t1 = asv.y + adv.y;
    e0 = t0 >= 0.f ? t0 : NEG_SLOPE * t0;
    e1 = t1 >= 0.f ? t1 : NEG_SLOPE * t1;
  }
  float m0 = wmax32(e0), m1 = wmax32(e1);
  float p0 = (s >= 0) ? __expf(e0 - m0) : 0.f;   // unnormalized
  float p1 = (s >= 0) ? __expf(e1 - m1) : 0.f;
  int g = l32 >> 4, c = l32 & 15;
  bool hsel = (c < 8);
  const uint4* hp = (const uint4*)h1b;
  v2f acc[4] = {{0.f,0.f},{0.f,0.f},{0.f,0.f},{0.f,0.f}};
  float dn = 0.f;
  // phase 1: j in [0,16)  -- all shuffles first, then 8 gathers in flight
  {
    int sj[8]; float pv[8];
    #pragma unroll
    for (int b = 0; b < 8; b++){
      int j = 2 * b + g;
      sj[b] = __shfl(s, j, 32);
      float q0 = __shfl(p0, j, 32);
      float q1 = __shfl(p1, j, 32);
      pv[b] = hsel ? q0 : q1;
    }
    uint4 v[8];
    #pragma unroll
    for (int b = 0; b < 8; b++){
      if (2 * b + g < ne) v[b] = hp[(size_t)sj[b] * 16 + c];
    }
    #pragma unroll
    for (int b = 0; b < 8; b++){
      if (2 * b + g < ne){
        v2f aw = {pv[b], pv[b]};
        acc[0] = aw * up2(v[b].x) + acc[0];
        acc[1] = aw * up2(v[b].y) + acc[1];
        acc[2] = aw * up2(v[b].z) + acc[2];
        acc[3] = aw * up2(v[b].w) + acc[3];
        dn += pv[b];
      }
    }
  }
  // phase 2: j in [16,32)
  if (ne > 16){
    int sj[8]; float pv[8];
    #pragma unroll
    for (int b = 0; b < 8; b++){
      int j = 16 + 2 * b + g;
      sj[b] = __shfl(s, j, 32);
      float q0 = __shfl(p0, j, 32);
      float q1 = __shfl(p1, j, 32);
      pv[b] = hsel ? q0 : q1;
    }
    uint4 v[8];
    #pragma unroll
    for (int b = 0; b < 8; b++){
      if (16 + 2 * b + g < ne) v[b] = hp[(size_t)sj[b] * 16 + c];
    }
    #pragma unroll
    for (int b = 0; b < 8; b++){
      if (16 + 2 * b + g < ne){
        v2f aw = {pv[b], pv[b]};
        acc[0] = aw * up2(v[b].x) + acc[0];
        acc[1] = aw * up2(v[b].y) + acc[1];
        acc[2] = aw * up2(v[b].z) + acc[2];
        acc[3] = aw * up2(v[b].w) + acc[3];
        dn += pv[b];
      }
    }
  }
  float accf[8] = {acc[0][0], acc[0][1], acc[1][0], acc[1][1],
                   acc[2][0], acc[2][1], acc[3][0], acc[3][1]};
  #pragma unroll
  for (int i = 0; i < 8; i++) accf[i] += __shfl_xor(accf[i], 16, 32);
  dn += __shfl_xor(dn, 16, 32);
  float inv = __builtin_amdgcn_rcpf(dn);   // dn >= 1 (self-loop) when ok
  float outv[8];
  #pragma unroll
  for (int i = 0; i < 8; i++){
    float r = accf[i] * inv;
    float o = __shfl_xor(r, 8, 32);
    outv[i] = 0.5f * (r + o);
  }
  if (ok && l32 < 8){
    unsigned short hb[8];
    float rr[8];
    #pragma unroll
    for (int i = 0; i < 8; i++){
      float v = outv[i] + b1[l32 * 8 + i];
      rr[i] = v > 0.f ? v : __expf(v) - 1.0f;
      hb[i] = f2bf(rr[i]);
    }
    uint4 pk;
    pk.x = (unsigned)hb[0] | ((unsigned)hb[1] << 16);
    pk.y = (unsigned)hb[2] | ((unsigned)hb[3] << 16);
    pk.z = (unsigned)hb[4] | ((unsigned)hb[5] << 16);
    pk.w = (unsigned)hb[6] | ((unsigned)hb[7] << 16);
    *(uint4*)&x1b[(size_t)d * 64 + l32 * 8] = pk;
    float sd = 0.f, dd = 0.f;
    #pragma unroll
    for (int i = 0; i < 8; i++){
      sd += rr[i] * w2a[l32 * 8 + i];
      dd += rr[i] * w2b[l32 * 8 + i];
    }
    sd += __shfl_xor(sd, 1, 32); dd += __shfl_xor(dd, 1, 32);
    sd += __shfl_xor(sd, 2, 32); dd += __shfl_xor(dd, 2, 32);
    sd += __shfl_xor(sd, 4, 32); dd += __shfl_xor(dd, 4, 32);
    if (l32 == 0){
      aa2[(size_t)d * 2]     = sd;
      aa2[(size_t)d * 2 + 1] = dd;
    }
  }
}

__device__ void agg2_one64(int d, int lane, const int* __restrict__ row_ptr,
                           const unsigned* __restrict__ sorted, const float* __restrict__ aa,
                           const unsigned short* __restrict__ xb,
                           unsigned short* __restrict__ y1b){
  int rp0 = row_ptr[d];
  int deg = row_ptr[d + 1] - rp0;
  float ad = aa[d * 2 + 1];
  int s = -1;
  if (lane < deg) s = (int)(sorted[rp0 + lane] & 0xffffu);
  else if (lane == deg) s = d;
  float e = -INFINITY;
  if (s >= 0){
    float t = aa[s * 2 + 0] + ad;
    e = t >= 0.f ? t : NEG_SLOPE * t;
  }
  float m = wmax(e);
  float p = (s >= 0) ? __expf(e - m) : 0.f;
  float al = p * __builtin_amdgcn_rcpf(wsum(p) + 1e-16f);
  int ne = deg + 1;
  int g = lane >> 3, c = lane & 7;
  const uint4* hp = (const uint4*)xb;
  v2f acc[4] = {{0.f,0.f},{0.f,0.f},{0.f,0.f},{0.f,0.f}};
  for (int j0 = 0; j0 < ne; j0 += 32){
    uint4 v[4]; float av[4];
    #pragma unroll
    for (int b = 0; b < 4; b++){
      int j = j0 + b * 8 + g;
      int sj = __shfl(s, j);
      av[b] = __shfl(al, j);
      if (j < ne) v[b] = hp[(size_t)sj * 8 + c];
    }
    #pragma unroll
    for (int b = 0; b < 4; b++){
      if (j0 + b * 8 + g < ne){
        v2f aw = {av[b], av[b]};
        acc[0] = aw * up2(v[b].x) + acc[0];
        acc[1] = aw * up2(v[b].y) + acc[1];
        acc[2] = aw * up2(v[b].z) + acc[2];
        acc[3] = aw * up2(v[b].w) + acc[3];
      }
    }
  }
  float accf[8] = {acc[0][0], acc[0][1], acc[1][0], acc[1][1],
                   acc[2][0], acc[2][1], acc[3][0], acc[3][1]};
  #pragma unroll
  for (int i = 0; i < 8; i++){
    accf[i] += __shfl_xor(accf[i], 8);
    accf[i] += __shfl_xor(accf[i], 16);
    accf[i] += __shfl_xor(accf[i], 32);
  }
  if (lane < 8){
    unsigned short hb[8];
    #pragma unroll
    for (int i = 0; i < 8; i++) hb[i] = f2bf(accf[i]);
    uint4 pk;
    pk.x = (unsigned)hb[0] | ((unsigned)hb[1] << 16);
    pk.y = (unsigned)hb[2] | ((unsigned)hb[3] << 16);
    pk.z = (unsigned)hb[4] | ((unsigned)hb[5] << 16);
    pk.w = (unsigned)hb[6] | ((unsigned)hb[7] << 16);
    *(uint4*)&y1b[(size_t)d * 64 + lane * 8] = pk;
  }
}

__global__ __launch_bounds__(512) void agg_layer2(const int* __restrict__ row_ptr,
    const unsigned* __restrict__ sorted, const float* __restrict__ aa,
    const unsigned short* __restrict__ xb, unsigned short* __restrict__ y1b,
    int n_nodes, int npair, int nsweep){
  int tid = threadIdx.x;
  int lane = tid & 63;
  if ((int)blockIdx.x >= npair){
    int sw = (blockIdx.x - npair) * 8 + (tid >> 6);
    int chunk = (n_nodes + nsweep - 1) / nsweep;
    int a = sw * chunk;
    int bnd = a + chunk; if (bnd > n_nodes) bnd = n_nodes;
    for (int i0 = a; i0 < bnd; i0 += 64){
      int idx = i0 + lane;
      int dg = 0;
      if (idx < bnd) dg = row_ptr[idx + 1] - row_ptr[idx];
      unsigned long long m = __ballot(dg > 31);
      while (m){
        int bit = __ffsll((long long)m) - 1;
        m &= m - 1;
        agg2_one64(i0 + bit, lane, row_ptr, sorted, aa, xb, y1b);
      }
    }
    return;
  }
  int wid = (blockIdx.x << 3) + (tid >> 6);
  int half = lane >> 5, l32 = lane & 31;
  int d = wid * 2 + half;
  if (wid * 2 >= n_nodes) return;
  bool valid = d < n_nodes;
  int rp0 = 0, deg = -1;
  if (valid){ rp0 = row_ptr[d]; deg = row_ptr[d + 1] - rp0; }
  bool ok = valid && deg <= 31;
  int ne = ok ? deg + 1 : 0;
  int s = -1;
  if (ok){
    if (l32 < deg) s = (int)(sorted[rp0 + l32] & 0xffffu);
    else if (l32 == deg) s = d;
  }
  float ad = valid ? aa[d * 2 + 1] : 0.f;
  float e = -INFINITY;
  if (s >= 0){
    float t = aa[s * 2 + 0] + ad;
    e = t >= 0.f ? t : NEG_SLOPE * t;
  }
  float m = wmax32(e);
  float p = (s >= 0) ? __expf(e - m) : 0.f;   // unnormalized
  int g = l32 >> 3, c = l32 & 7;
  const uint4* hp = (const uint4*)xb;
  v2f acc[4] = {{0.f,0.f},{0.f,0.f},{0.f,0.f},{0.f,0.f}};
  float dn = 0.f;
  // single phase: j = 4*b + g covers j in [0,32) -- 8 gathers in flight
  {
    int sj[8]; float pv[8];
    #pragma unroll
    for (int b = 0; b < 8; b++){
      int j = 4 * b + g;
      sj[b] = __shfl(s, j, 32);
      pv[b] = __shfl(p, j, 32);
    }
    uint4 v[8];
    #pragma unroll
    for (int b = 0; b < 8; b++){
      if (4 * b + g < ne) v[b] = hp[(size_t)sj[b] * 8 + c];
    }
    #pragma unroll
    for (int b = 0; b < 8; b++){
      if (4 * b + g < ne){
        v2f aw = {pv[b], pv[b]};
        acc[0] = aw * up2(v[b].x) + acc[0];
        acc[1] = aw * up2(v[b].y) + acc[1];
        acc[2] = aw * up2(v[b].z) + acc[2];
        acc[3] = aw * up2(v[b].w) + acc[3];
        dn += pv[b];
      }
    }
  }
  float accf[8] = {acc[0][0], acc[0][1], acc[1][0], acc[1][1],
                   acc[2][0], acc[2][1], acc[3][0], acc[3][1]};
  #pragma unroll
  for (int i = 0; i < 8; i++){
    accf[i] += __shfl_xor(accf[i], 8, 32);
    accf[i] += __shfl_xor(accf[i], 16, 32);
  }
  dn += __shfl_xor(dn, 8, 32);
  dn += __shfl_xor(dn, 16, 32);
  float inv = __builtin_amdgcn_rcpf(dn);   // dn >= 1 (self-loop) when ok
  if (ok && l32 < 8){
    unsigned short hb[8];
    #pragma unroll
    for (int i = 0; i < 8; i++) hb[i] = f2bf(accf[i] * inv);
    uint4 pk;
    pk.x = (unsigned)hb[0] | ((unsigned)hb[1] << 16);
    pk.y = (unsigned)hb[2] | ((unsigned)hb[3] << 16);
    pk.z = (unsigned)hb[4] | ((unsigned)hb[5] << 16);
    pk.w = (unsigned)hb[6] | ((unsigned)hb[7] << 16);
    *(uint4*)&y1b[(size_t)d * 64 + l32 * 8] = pk;
  }
}

extern "C" void kernel_launch(void* const* d_in, const int* in_sizes, int n_in,
                              void* d_out, int out_size, void* d_ws, size_t ws_size,
                              hipStream_t stream){
  const float* x     = (const float*)d_in[0];
  const int*   ei    = (const int*)d_in[1];
  const float* W1    = (const float*)d_in[2];
  const float* asrc1 = (const float*)d_in[3];
  const float* adst1 = (const float*)d_in[4];
  const float* b1    = (const float*)d_in[5];
  const float* W2    = (const float*)d_in[6];
  const float* asrc2 = (const float*)d_in[7];
  const float* adst2 = (const float*)d_in[8];
  const float* b2    = (const float*)d_in[9];
  float* out = (float*)d_out;
  int N = in_sizes[0] / IN_DIM;   // 50000 (< 65536 for 16-bit packing)
  int E = in_sizes[1] / 2;
  int NG = (N + 255) >> 8;                  // coarse bins (196)
  int NBLK = (E + CHUNK - 1) / CHUNK;       // scatter blocks (196)
  int npair = (N + 15) / 16;                // 2 nodes/wave, 8 waves/block
  int GT = (N + 63) / 64;                   // total 64-row gemm1 blocks (782)
  int GA = GT / 2;                          // first half with scatter
  int GB = GT - GA;                         // second half with group_sort

  char* p = (char*)d_ws;
  unsigned short* h1b = (unsigned short*)p;  p += (size_t)N * 128 * 2;
  unsigned short* x1b = (unsigned short*)p;  p += (size_t)N * 64 * 2;
  unsigned short* y1b = (unsigned short*)p;  p += (size_t)N * 64 * 2;
  float* aa1 = (float*)p;                    p += (size_t)N * 4 * 4;
  float* aa2 = (float*)p;                    p += (size_t)N * 2 * 4;
  unsigned* binned = (unsigned*)p;           p += (size_t)E * 4;
  unsigned* sorted = (unsigned*)p;           p += (size_t)E * 4;
  int* row_ptr   = (int*)p;                  p += (size_t)(N + 1) * 4;
  int* binCnt    = (int*)p;                  p += 256 * 4;
  int* binOff    = (int*)p;                  p += 256 * 4;
  unsigned short* W1t = (unsigned short*)p;  p += 128 * 128 * 2;
  unsigned short* W2t = (unsigned short*)p;  p += 64 * 64 * 2;
  float* w2a = (float*)p;                    p += 64 * 4;
  float* w2b = (float*)p;

  hipMemsetAsync(binCnt, 0, 512 * sizeof(int), stream);   // binCnt + binOff
  prep<<<NBLK + 81, 256, 0, stream>>>(ei, E, NBLK, binCnt, W1, W2, asrc2, adst2,
                                      W1t, W2t, w2a, w2b, row_ptr, N);
  sort_gemm_a<<<NBLK + GA, 256, 0, stream>>>(ei, E, binCnt, binOff, binned,
                                             NBLK, x, W1t, asrc1, adst1, h1b, aa1, N);
  sort_gemm_b<<<NG + GB, 256, 0, stream>>>(binned, binCnt, sorted, row_ptr, N,
                                           NG, GA, x, W1t, asrc1, adst1, h1b, aa1, N);
  agg_layer1<<<npair + NBIGBLK, 512, 0, stream>>>(row_ptr, sorted, aa1, h1b, b1,
                                                  w2a, w2b, x1b, aa2,
                                                  N, npair, NBIGBLK * 8);
  agg_layer2<<<npair + NBIGBLK, 512, 0, stream>>>(row_ptr, sorted, aa2, x1b, y1b,
                                                  N, npair, NBIGBLK * 8);
  gemm_out<<<(N + 127) / 128, 512, 0, stream>>>(y1b, W2t, b2, out, N);
}